// Round 1
// 934.793 us; speedup vs baseline: 1.0426x; 1.0426x over previous
//
#include <hip/hip_runtime.h>
#include <cmath>

typedef unsigned short u16;
typedef __attribute__((ext_vector_type(8))) __bf16 bf16x8;
typedef __attribute__((ext_vector_type(4))) float f32x4;

#define DEV static __device__ __forceinline__

DEV float b2f(u16 u){ union{unsigned i; float f;} v; v.i=((unsigned)u)<<16; return v.f; }
DEV u16 f2b(float f){ union{float f; unsigned i;} v; v.f=f; unsigned r = v.i + 0x7FFFu + ((v.i>>16)&1u); return (u16)(r>>16); }

#define GLL(g,l) __builtin_amdgcn_global_load_lds((const __attribute__((address_space(1))) void*)(g), (__attribute__((address_space(3))) void*)(l), 16, 0, 0)

// ---------------- tiny utility kernels ----------------
__global__ void k_zero(float* p, int n){ int i = blockIdx.x*256+threadIdx.x; if(i<n) p[i]=0.f; }

// convert W_so, W_co, W_m2 to bf16 (the non-folded weights)
__global__ void k_cvt3(const float* __restrict__ s0,const float* __restrict__ s1,
                       const float* __restrict__ s2, u16* __restrict__ d){
  int i = blockIdx.x*256 + threadIdx.x;
  if (i >= 294912) return;
  const float* s; int off;
  if      (i < 65536){ s=s0; off=0; }
  else if (i < 131072){ s=s1; off=65536; }
  else                { s=s2; off=131072; }
  d[i] = f2b(s[i-off]);
}

// ---------------- GN->conv fold: per-batch weights + bias ----------------
// Wb[b][o][k] = W[o][k]*g[k]*rs[b,gr(k)];  biasb[b][o] = base[o] + sum_k W[o][k]*(beta[k]-mu*rs*g[k])
__global__ void k_fold(const float* __restrict__ W, const float* __restrict__ g,
                       const float* __restrict__ beta, const float* __restrict__ base,
                       const float* __restrict__ stats, u16* __restrict__ Wb,
                       float* __restrict__ biasb, int O, int K, int chsh, float inv_n){
  const int o = blockIdx.x, b = blockIdx.y;
  const int tid = threadIdx.x;
  float bp = 0.f;
  for (int k = tid; k < K; k += 256){
    const int gr = k >> chsh;
    const float s = stats[(b*32+gr)*2], s2 = stats[(b*32+gr)*2+1];
    const float mu = s*inv_n;
    const float rs = rsqrtf(s2*inv_n - mu*mu + 1e-5f);
    const float w = W[(long)o*K + k];
    const float gg = g[k]*rs;
    Wb[((long)b*O + o)*K + k] = f2b(w*gg);
    bp += w*(beta[k] - mu*gg);
  }
  __shared__ float red[256];
  red[tid] = bp; __syncthreads();
  for (int off=128; off>0; off>>=1){ if (tid<off) red[tid]+=red[tid+off]; __syncthreads(); }
  if (tid==0) biasb[b*O+o] = red[0] + (base ? base[o] : 0.f);
}

// ---------------- transpose [B,C,T] -> [B,T,C] raw bf16 + fused GN raw sums ----------------
template<int CHSH>
__global__ void k_transs(const float* __restrict__ src, u16* __restrict__ dstRaw,
                         float* __restrict__ stat, int C){
  const int b = blockIdx.z;
  const int t0 = blockIdx.x*64, c0 = blockIdx.y*64;
  const int tid = threadIdx.x;
  __shared__ float tile[64][65];
  __shared__ float grp[16];
  if (tid < 16) grp[tid] = 0.f;
  float s_acc[4], s2_acc[4];
  #pragma unroll
  for (int p=0;p<4;p++){
    const int cc = (tid>>4) + p*16, tt = (tid&15)*4;
    const float4 v = *(const float4*)&src[((long)b*C + c0+cc)*8192 + t0+tt];
    tile[cc][tt+0]=v.x; tile[cc][tt+1]=v.y; tile[cc][tt+2]=v.z; tile[cc][tt+3]=v.w;
    s_acc[p]  = v.x+v.y+v.z+v.w;
    s2_acc[p] = v.x*v.x+v.y*v.y+v.z*v.z+v.w*v.w;
  }
  __syncthreads();
  // per-channel reduce within 16-lane groups (lanes 0-15,16-31,... share one channel)
  #pragma unroll
  for (int p=0;p<4;p++){
    float s = s_acc[p], s2 = s2_acc[p];
    #pragma unroll
    for (int m=1; m<16; m<<=1){ s += __shfl_xor(s, m); s2 += __shfl_xor(s2, m); }
    if ((tid&15)==0){
      const int gl = ((tid>>4) + p*16) >> CHSH;
      atomicAdd(&grp[gl*2],   s);
      atomicAdd(&grp[gl*2+1], s2);
    }
  }
  #pragma unroll
  for (int p=0;p<4;p++){
    const int tt = (tid>>4) + p*16, c4 = (tid&15)*4;
    u16 rbi[4];
    #pragma unroll
    for (int j=0;j<4;j++) rbi[j] = f2b(tile[c4+j][tt]);
    ushort4 rv; rv.x=rbi[0]; rv.y=rbi[1]; rv.z=rbi[2]; rv.w=rbi[3];
    *(ushort4*)&dstRaw[((long)b*8192 + t0+tt)*C + c0+c4] = rv;
  }
  __syncthreads();
  const int ngr = 64>>CHSH;
  if (tid < ngr*2){
    atomicAdd(&stat[((b*32) + (c0>>CHSH))*2 + tid], grp[tid]);
  }
}

// ---------------- MFMA GEMM: out[t,o] = sum_k A[t,k]*W[o,k] ----------------
// wsb/bsb: per-batch strides for folded weights/bias (0 for shared)
template<bool OUTB, bool BIAS, bool SILU, bool RES, bool STATS, bool SPLIT>
__global__ __launch_bounds__(256,2) void k_gemm(
    const u16* __restrict__ A, const u16* __restrict__ W,
    float* __restrict__ outF, u16* __restrict__ outB,
    const float* __restrict__ bias, const u16* __restrict__ res,
    float* __restrict__ stat, int K, int O, long wsb, int bsb)
{
  __shared__ u16 As[128*64];
  __shared__ u16 Ws[128*64];
  __shared__ float sb[128][2];
  const int tid = threadIdx.x;
  const int wv = tid>>6, lane = tid&63;
  const long t0 = (long)blockIdx.y*128;
  const int o0 = blockIdx.x*128;
  const int bb = (int)(t0>>13);
  const u16* Wp = W + (long)bb*wsb;
  const int wt = (wv>>1)*64, wo = (wv&1)*64;
  const int lr = lane>>3, lc = (lane&7)*8;
  f32x4 acc[4][4] = {};
  for (int kc = 0; kc < K; kc += 64){
    #pragma unroll
    for (int it = 0; it < 4; ++it){
      const int r = wv*32 + it*8;
      GLL(A + (t0 + r + lr)*(long)K + kc + lc, &As[r*64]);
      GLL(Wp + (long)(o0 + r + lr)*K + kc + lc, &Ws[r*64]);
    }
    __syncthreads();
    #pragma unroll
    for (int ks=0; ks<2; ++ks){
      const int kb = ks*32 + (lane>>4)*8;
      bf16x8 af[4], bfr[4];
      #pragma unroll
      for (int i=0;i<4;i++) af[i]  = *(const bf16x8*)&As[(wt + i*16 + (lane&15))*64 + kb];
      #pragma unroll
      for (int j=0;j<4;j++) bfr[j] = *(const bf16x8*)&Ws[(wo + j*16 + (lane&15))*64 + kb];
      #pragma unroll
      for (int i=0;i<4;i++)
        #pragma unroll
        for (int j=0;j<4;j++)
          acc[i][j] = __builtin_amdgcn_mfma_f32_16x16x32_bf16(af[i], bfr[j], acc[i][j], 0, 0, 0);
    }
    __syncthreads();
  }
  if (STATS){
    if (tid < 128){ sb[tid][0]=0.f; sb[tid][1]=0.f; }
    __syncthreads();
  }
  const int q = lane>>4, cc = lane&15;
  #pragma unroll
  for (int j=0;j<4;j++){
    const int o = o0 + wo + j*16 + cc;
    const float bv = BIAS ? bias[bsb*bb + o] : 0.f;
    float ts=0.f, ts2=0.f;
    #pragma unroll
    for (int i=0;i<4;i++){
      const long tb = t0 + wt + i*16 + q*4;
      #pragma unroll
      for (int r=0;r<4;r++){
        float v = acc[i][j][r] + bv;
        if (SILU) v = v * (1.f/(1.f + __expf(-v)));
        long idx;
        if (SPLIT) idx = ((long)(o>>8)<<24) + (tb + r)*256 + (o&255);
        else       idx = (tb + r)*(long)O + o;
        if (RES) v += b2f(res[idx]);
        if (STATS){ ts += v; ts2 += v*v; }
        if (OUTB) outB[idx] = f2b(v); else outF[idx] = v;
      }
    }
    if (STATS){
      const int ol = wo + j*16 + cc;
      atomicAdd(&sb[ol][0], ts);
      atomicAdd(&sb[ol][1], ts2);
    }
  }
  if (STATS){
    __syncthreads();
    if (tid < 16){
      float u=0.f, u2=0.f;
      #pragma unroll
      for (int j2=0;j2<8;j2++){ u += sb[tid*8+j2][0]; u2 += sb[tid*8+j2][1]; }
      atomicAdd(&stat[(bb*32 + (o0>>3) + tid)*2],   u);
      atomicAdd(&stat[(bb*32 + (o0>>3) + tid)*2+1], u2);
    }
  }
}

// ---------------- ctx partials + per-block ksum partial; dense [65536,256] k/v inputs ----------------
__global__ __launch_bounds__(256,2) void k_ctx(const u16* __restrict__ kp, const u16* __restrict__ vp,
                                               float* __restrict__ part){
  const int tid = threadIdx.x;
  const int b = blockIdx.x >> 6, seg = blockIdx.x & 63;
  const int h = tid>>5, d = tid&31;
  __shared__ u16 kb[16][256];
  __shared__ float vf[16][260];
  float acc[32];
  #pragma unroll
  for (int e=0;e<32;e++) acc[e]=0.f;
  float ks = 0.f;
  const long rb = (long)b*8192 + seg*128;
  const int w = tid>>6, sub = tid&63;
  for (int tc=0; tc<128; tc+=16){
    #pragma unroll
    for (int p=0;p<4;p++){
      const int row = p*4 + w;
      const long rowbase = (rb + tc + row)*256;
      if (sub < 32){
        uint4 val = *(const uint4*)(kp + rowbase + sub*8);
        *(uint4*)&kb[row][sub*8] = val;
      } else {
        const int s2 = sub-32;
        uint4 val = *(const uint4*)(vp + rowbase + s2*8);
        const u16* vs = (const u16*)&val;
        float4 f0 = {b2f(vs[0]),b2f(vs[1]),b2f(vs[2]),b2f(vs[3])};
        float4 f1 = {b2f(vs[4]),b2f(vs[5]),b2f(vs[6]),b2f(vs[7])};
        *(float4*)&vf[row][s2*8] = f0;
        *(float4*)&vf[row][s2*8+4] = f1;
      }
    }
    __syncthreads();
    #pragma unroll
    for (int r=0;r<16;r++){
      const float kpv = __expf(b2f(kb[r][h*32+d]));
      ks += kpv;
      #pragma unroll
      for (int e4=0;e4<8;e4++){
        const float4 v4 = *(const float4*)&vf[r][h*32+e4*4];
        acc[e4*4+0] += kpv*v4.x; acc[e4*4+1] += kpv*v4.y;
        acc[e4*4+2] += kpv*v4.z; acc[e4*4+3] += kpv*v4.w;
      }
    }
    __syncthreads();
  }
  float* pb = part + (long)blockIdx.x*8448;
  #pragma unroll
  for (int e=0;e<32;e++) pb[e*256 + tid] = acc[e];
  pb[8192 + tid] = ks;
}

// ---------------- reduce ctx partials + ksum partials ----------------
__global__ void k_ctxred(const float* __restrict__ part, float* __restrict__ ctx,
                         float* __restrict__ ksumF){
  if (blockIdx.x >= 256){
    const int j = (blockIdx.x-256)*256 + threadIdx.x;
    #pragma unroll
    for (int q=0;q<4;q++){
      const int idx = j*4+q;
      const int b = idx>>8, cch = idx&255;
      float s=0.f;
      for (int g=0; g<64; g++) s += part[((long)(b*64+g))*8448 + 8192 + cch];
      ksumF[idx] = s;
    }
    return;
  }
  const int i = blockIdx.x*256 + threadIdx.x;
  const int b = i>>13, r = i&8191;
  float s=0.f;
  for (int g=0; g<64; g++) s += part[((long)(b*64+g))*8448 + r];
  ctx[i] = s;
}

// ---------------- attn out: q-softmax contraction against ctx/ksum; q dense [65536,256] ----
__global__ void k_attnout(const u16* __restrict__ q, const float* __restrict__ ctx,
                          const float* __restrict__ ksumF, u16* __restrict__ out){
  const int b = blockIdx.x >> 8, t0 = (blockIdx.x & 255)*32;
  __shared__ float cs[8512];   // [h][d][e] strides 1064/33/1
  for (int i=threadIdx.x; i<8192; i+=256){
    const int e=i>>8, cch=i&255;
    cs[(cch>>5)*1064 + (cch&31)*33 + e] = ctx[(b<<13) + i] / ksumF[b*256 + cch];
  }
  __syncthreads();
  const int t = t0 + (threadIdx.x>>3), h = threadIdx.x&7;
  const u16* qp = q + ((long)b*8192 + t)*256 + h*32;
  uint4 qv[4];
  #pragma unroll
  for (int j=0;j<4;j++) qv[j] = ((const uint4*)qp)[j];
  const u16* qs = (const u16*)qv;
  float qe[32]; float ssum = 0.f;
  #pragma unroll
  for (int dd=0; dd<32; dd++){ qe[dd] = __expf(b2f(qs[dd])); ssum += qe[dd]; }
  const float inv = 0.17677669529663687f / ssum;
  float o[32];
  #pragma unroll
  for (int e=0;e<32;e++) o[e]=0.f;
  const float* ch = &cs[h*1064];
  #pragma unroll
  for (int dd=0; dd<32; dd++){
    const float w = qe[dd]*inv;
    #pragma unroll
    for (int e=0;e<32;e++) o[e] += w * ch[dd*33+e];
  }
  u16 ob[32];
  #pragma unroll
  for (int e=0;e<32;e++) ob[e] = f2b(o[e]);
  uint4* op = (uint4*)(out + ((long)b*8192 + t)*256 + h*32);
  const uint4* obv = (const uint4*)ob;
  #pragma unroll
  for (int j=0;j<4;j++) op[j] = obv[j];
}

// ---------------- x_new = GN(conv)*g+b + x (bf16 residual, in-place) + stats of x_new ----------------
__global__ void k_gnres(const u16* __restrict__ conv, u16* __restrict__ xr,
                        const float* __restrict__ sums_in, float* __restrict__ sums_out,
                        const float* __restrict__ g, const float* __restrict__ bt){
  const int blk = blockIdx.x;
  const int b = blk>>7;
  const long base = (long)blk*4096;
  const int tid = threadIdx.x;
  const int c0 = (tid<<2)&255;
  const int gr = c0>>3;
  const float s = sums_in[(b*32+gr)*2], s2 = sums_in[(b*32+gr)*2+1];
  const float mu = s*(1.f/65536.f);
  const float rs = rsqrtf(s2*(1.f/65536.f) - mu*mu + 1e-5f);
  float gg[4], bb[4];
  #pragma unroll
  for (int j=0;j<4;j++){ gg[j] = g[c0+j]*rs; bb[j] = bt[c0+j] - mu*gg[j]; }
  float ts=0.f, ts2=0.f;
  for (int it=0; it<16; ++it){
    const long i4 = base + it*256 + tid;
    ushort4 cv = ((const ushort4*)conv)[i4];
    ushort4 rv = ((const ushort4*)xr)[i4];
    float ov[4];
    const float ci[4] = {b2f(cv.x),b2f(cv.y),b2f(cv.z),b2f(cv.w)};
    const float ri[4] = {b2f(rv.x),b2f(rv.y),b2f(rv.z),b2f(rv.w)};
    #pragma unroll
    for (int j=0;j<4;j++){
      ov[j] = ci[j]*gg[j] + bb[j] + ri[j];
      ts += ov[j]; ts2 += ov[j]*ov[j];
    }
    ushort4 o4; o4.x=f2b(ov[0]); o4.y=f2b(ov[1]); o4.z=f2b(ov[2]); o4.w=f2b(ov[3]);
    ((ushort4*)xr)[i4] = o4;
  }
  __shared__ float grp[32][2];
  if (tid<32){ grp[tid][0]=0.f; grp[tid][1]=0.f; }
  __syncthreads();
  atomicAdd(&grp[gr][0], ts);
  atomicAdd(&grp[gr][1], ts2);
  __syncthreads();
  if (tid<32){
    atomicAdd(&sums_out[(b*32+tid)*2],   grp[tid][0]);
    atomicAdd(&sums_out[(b*32+tid)*2+1], grp[tid][1]);
  }
}

// ---------------- final transpose [B,T,256] -> [B,256,T] ----------------
__global__ void k_final(const float* __restrict__ y, float* __restrict__ out){
  const int b = blockIdx.z;
  const int t0 = blockIdx.x*64, c0 = blockIdx.y*64;
  __shared__ float tile[64][65];
  #pragma unroll
  for (int p=0;p<4;p++){
    const int tt = (threadIdx.x>>4) + p*16, c4 = (threadIdx.x&15)*4;
    const float4 v = *(const float4*)&y[((long)b*8192 + t0+tt)*256 + c0+c4];
    tile[c4+0][tt]=v.x; tile[c4+1][tt]=v.y; tile[c4+2][tt]=v.z; tile[c4+3][tt]=v.w;
  }
  __syncthreads();
  #pragma unroll
  for (int p=0;p<4;p++){
    const int cc = (threadIdx.x>>4) + p*16, t4 = (threadIdx.x&15)*4;
    float4 v = {tile[cc][t4], tile[cc][t4+1], tile[cc][t4+2], tile[cc][t4+3]};
    *(float4*)&out[((long)b*256 + c0+cc)*8192 + t0+t4] = v;
  }
}

extern "C" void kernel_launch(void* const* d_in, const int* in_sizes, int n_in,
                              void* d_out, int out_size, void* d_ws, size_t ws_size,
                              hipStream_t stream){
  (void)in_sizes; (void)n_in; (void)out_size; (void)ws_size;
  const float* x   = (const float*)d_in[0];
  const float* c   = (const float*)d_in[1];
  const float* W_qkv=(const float*)d_in[2];
  const float* W_so =(const float*)d_in[3];
  const float* b_so =(const float*)d_in[4];
  const float* sa_g =(const float*)d_in[5];
  const float* sa_b =(const float*)d_in[6];
  const float* W_cq =(const float*)d_in[7];
  const float* W_ckv=(const float*)d_in[8];
  const float* W_co =(const float*)d_in[9];
  const float* b_co =(const float*)d_in[10];
  const float* ca_g =(const float*)d_in[11];
  const float* ca_b =(const float*)d_in[12];
  const float* W_m1 =(const float*)d_in[13];
  const float* b_m1 =(const float*)d_in[14];
  const float* W_m2 =(const float*)d_in[15];
  const float* b_m2 =(const float*)d_in[16];
  const float* nm_g =(const float*)d_in[17];
  const float* nm_b =(const float*)d_in[18];
  const float* nm1_g=(const float*)d_in[19];
  const float* nm1_b=(const float*)d_in[20];
  const float* nm2_g=(const float*)d_in[21];
  const float* nm2_b=(const float*)d_in[22];
  const float* nm3_g=(const float*)d_in[23];
  const float* nm3_b=(const float*)d_in[24];
  float* out = (float*)d_out;

  char* ws = (char*)d_ws;
  const size_t MB = 1024ull*1024ull;
  // non-folded weights (bf16)
  u16* wSO = (u16*)ws;                 // 65536
  u16* wCO = wSO + 65536;              // 65536
  u16* wM2 = wCO + 65536;              // 163840
  // stats
  float* stats = (float*)(ws + 1*MB);
  float* xstat = stats;                // 512
  float* cstat = stats + 512;          // 512
  float* so_sum= stats + 1024;
  float* x1_sum= stats + 1536;
  float* co_sum= stats + 2048;
  float* x2_sum= stats + 2560;
  float* ksumF = stats + 3072;         // 2048
  float* ctxb  = stats + 8192;         // 65536
  // folded biases (fp32)
  float* bQKV = (float*)(ws + 2*MB);   // 8*768
  float* bCKV = bQKV + 6144;           // 8*512
  float* bCQ  = bCKV + 4096;           // 8*256
  float* bM1  = bCQ + 2048;            // 8*640
  // folded per-batch weights (bf16)
  u16* wQKVb = (u16*)(ws + 3*MB);      // 8*768*256 = 3 MB
  u16* wCKVb = (u16*)(ws + 6*MB);      // 8*512*512 = 4 MB
  u16* wCQb  = (u16*)(ws + 10*MB);     // 8*256*256 = 1 MB
  u16* wM1b  = (u16*)(ws + 11*MB);     // 8*640*256 = 2.5 MB
  // streams
  u16*   xT    = (u16*)(ws + 16*MB);   // [65536,256] bf16 raw residual (in-place)
  u16*   cT    = (u16*)(ws + 48*MB);   // [65536,512] bf16 raw transposed c
  float* part  = (float*)(ws + 112*MB);// [512][8448] fp32 partials
  u16*   qkvb  = (u16*)(ws + 136*MB);  // 3 x 2^24 bf16 (q,k,v; reused: cross-q, mlp hidden)
  u16*   kvb   = (u16*)(ws + 232*MB);  // 2 x 2^24 bf16 cross k,v (aliased convb/convF)
  u16*   convb = kvb;
  float* convF = (float*)kvb;
  u16*   attno = (u16*)(ws + 296*MB);  // [65536,256] bf16
  const long SEG = 1L<<24;

  k_zero<<<12,256,0,stream>>>(stats, 3072);
  k_cvt3<<<1152,256,0,stream>>>(W_so, W_co, W_m2, wSO);

  // ---- transpose + fused GN raw sums ----
  k_transs<3><<<dim3(128,4,8),256,0,stream>>>(x, xT, xstat, 256);
  k_transs<4><<<dim3(128,8,8),256,0,stream>>>(c, cT, cstat, 512);

  // ---- stage 1: self linear attention ----
  k_fold<<<dim3(768,8),256,0,stream>>>(W_qkv, nm_g, nm_b, nullptr, xstat, wQKVb, bQKV, 768, 256, 3, 1.f/65536.f);
  k_fold<<<dim3(512,8),256,0,stream>>>(W_ckv, nm3_g, nm3_b, nullptr, cstat, wCKVb, bCKV, 512, 512, 4, 1.f/131072.f);
  k_gemm<true,true,false,false,false,true><<<dim3(6,512),256,0,stream>>>(xT, wQKVb, nullptr, qkvb, bQKV, nullptr, nullptr, 256, 768, 196608, 768);
  k_ctx<<<512,256,0,stream>>>(qkvb+SEG, qkvb+2*SEG, part);
  k_ctxred<<<258,256,0,stream>>>(part, ctxb, ksumF);
  k_attnout<<<2048,256,0,stream>>>(qkvb, ctxb, ksumF, attno);
  k_gemm<true,true,false,false,true,false><<<dim3(2,512),256,0,stream>>>(attno, wSO, nullptr, convb, b_so, nullptr, so_sum, 256, 256, 0, 0);
  k_gnres<<<1024,256,0,stream>>>(convb, xT, so_sum, x1_sum, sa_g, sa_b);

  // ---- stage 2: cross linear attention ----
  k_fold<<<dim3(256,8),256,0,stream>>>(W_cq, nm1_g, nm1_b, nullptr, x1_sum, wCQb, bCQ, 256, 256, 3, 1.f/65536.f);
  k_gemm<true,true,false,false,false,false><<<dim3(2,512),256,0,stream>>>(xT, wCQb, nullptr, qkvb, bCQ, nullptr, nullptr, 256, 256, 65536, 256);
  k_gemm<true,true,false,false,false,true><<<dim3(4,512),256,0,stream>>>(cT, wCKVb, nullptr, kvb, bCKV, nullptr, nullptr, 512, 512, 262144, 512);
  k_ctx<<<512,256,0,stream>>>(kvb, kvb+SEG, part);
  k_ctxred<<<258,256,0,stream>>>(part, ctxb, ksumF);
  k_attnout<<<2048,256,0,stream>>>(qkvb, ctxb, ksumF, attno);
  k_gemm<true,true,false,false,true,false><<<dim3(2,512),256,0,stream>>>(attno, wCO, nullptr, convb, b_co, nullptr, co_sum, 256, 256, 0, 0);
  k_gnres<<<1024,256,0,stream>>>(convb, xT, co_sum, x2_sum, ca_g, ca_b);

  // ---- stage 3: SiLU MLP ----
  k_fold<<<dim3(640,8),256,0,stream>>>(W_m1, nm2_g, nm2_b, b_m1, x2_sum, wM1b, bM1, 640, 256, 3, 1.f/65536.f);
  k_gemm<true,true,true,false,false,false><<<dim3(5,512),256,0,stream>>>(xT, wM1b, nullptr, qkvb, bM1, nullptr, nullptr, 256, 640, 163840, 640);
  k_gemm<false,true,false,true,false,false><<<dim3(2,512),256,0,stream>>>(qkvb, wM2, convF, nullptr, b_m2, xT, nullptr, 640, 256, 0, 0);
  k_final<<<dim3(128,4,8),256,0,stream>>>(convF, out);
}

// Round 3
// 873.426 us; speedup vs baseline: 1.1159x; 1.0703x over previous
//
#include <hip/hip_runtime.h>
#include <cmath>

typedef unsigned short u16;
typedef __attribute__((ext_vector_type(8))) __bf16 bf16x8;
typedef __attribute__((ext_vector_type(4))) float f32x4;

#define DEV static __device__ __forceinline__

DEV float b2f(u16 u){ union{unsigned i; float f;} v; v.i=((unsigned)u)<<16; return v.f; }
DEV u16 f2b(float f){ union{float f; unsigned i;} v; v.f=f; unsigned r = v.i + 0x7FFFu + ((v.i>>16)&1u); return (u16)(r>>16); }

#define GLL(g,l) __builtin_amdgcn_global_load_lds((const __attribute__((address_space(1))) void*)(g), (__attribute__((address_space(3))) void*)(l), 16, 0, 0)

// ---------------- init: convert W_so|W_co|W_m2 to bf16 + zero stats ----------------
__global__ void k_init(const float* __restrict__ s0,const float* __restrict__ s1,
                       const float* __restrict__ s2, u16* __restrict__ d,
                       float* __restrict__ stats){
  const int bid = blockIdx.x;
  if (bid == 1152){
    #pragma unroll
    for (int j=0;j<12;j++){ const int idx=j*256+threadIdx.x; if (idx<3072) stats[idx]=0.f; }
    return;
  }
  const int i = bid*256 + threadIdx.x;
  const float* s; int off;
  if      (i < 65536){ s=s0; off=0; }
  else if (i < 131072){ s=s1; off=65536; }
  else                { s=s2; off=131072; }
  d[i] = f2b(s[i-off]);
}

// ---------------- GN->conv fold: per-batch weights + bias ----------------
// Wb[b][o][k] = W[o][k]*g[k]*rs[b,gr(k)];  biasb[b][o] = base[o] + sum_k W[o][k]*(beta[k]-mu*rs*g[k])
DEV void fold_body(const float* W, const float* g, const float* beta, const float* base,
                   const float* stats, u16* Wb, float* biasb, int O, int K, int chsh,
                   float inv_n, int o, int b){
  const int tid = threadIdx.x;
  float bp = 0.f;
  for (int k = tid; k < K; k += 256){
    const int gr = k >> chsh;
    const float s = stats[(b*32+gr)*2], s2 = stats[(b*32+gr)*2+1];
    const float mu = s*inv_n;
    const float rs = rsqrtf(s2*inv_n - mu*mu + 1e-5f);
    const float w = W[(long)o*K + k];
    const float gg = g[k]*rs;
    Wb[((long)b*O + o)*K + k] = f2b(w*gg);
    bp += w*(beta[k] - mu*gg);
  }
  __shared__ float red[256];
  red[tid] = bp; __syncthreads();
  for (int off=128; off>0; off>>=1){ if (tid<off) red[tid]+=red[tid+off]; __syncthreads(); }
  if (tid==0) biasb[b*O+o] = red[0] + (base ? base[o] : 0.f);
}

__global__ void k_fold(const float* __restrict__ W, const float* __restrict__ g,
                       const float* __restrict__ beta, const float* __restrict__ base,
                       const float* __restrict__ stats, u16* __restrict__ Wb,
                       float* __restrict__ biasb, int O, int K, int chsh, float inv_n){
  fold_body(W,g,beta,base,stats,Wb,biasb,O,K,chsh,inv_n,blockIdx.x,blockIdx.y);
}

// merged fold for QKV (O1 rows) + CKV (O2 rows)
__global__ void k_fold2(const float* __restrict__ W1, const float* __restrict__ g1,
                        const float* __restrict__ be1, const float* __restrict__ st1,
                        u16* __restrict__ Wb1, float* __restrict__ bb1, int O1, int K1, int chsh1, float inv1,
                        const float* __restrict__ W2, const float* __restrict__ g2,
                        const float* __restrict__ be2, const float* __restrict__ st2,
                        u16* __restrict__ Wb2, float* __restrict__ bb2, int O2, int K2, int chsh2, float inv2){
  const int o = blockIdx.x, b = blockIdx.y;
  if (o < O1) fold_body(W1,g1,be1,nullptr,st1,Wb1,bb1,O1,K1,chsh1,inv1,o,b);
  else        fold_body(W2,g2,be2,nullptr,st2,Wb2,bb2,O2,K2,chsh2,inv2,o-O1,b);
}

// ---------------- transpose [B,C,T] -> [B,T,C] raw bf16 + fused GN raw sums (x and c merged) ----
__global__ void k_transs(const float* __restrict__ xsrc, const float* __restrict__ csrc,
                         u16* __restrict__ xdst, u16* __restrict__ cdst,
                         float* __restrict__ xstat, float* __restrict__ cstat){
  const int b = blockIdx.z;
  const int gy = blockIdx.y;
  const float* src; u16* dst; float* stat; int C, chsh, c0;
  if (gy < 4){ src=xsrc; dst=xdst; stat=xstat; C=256; chsh=3; c0=gy*64; }
  else       { src=csrc; dst=cdst; stat=cstat; C=512; chsh=4; c0=(gy-4)*64; }
  const int t0 = blockIdx.x*64;
  const int tid = threadIdx.x;
  __shared__ float tile[64][65];
  __shared__ float grp[16];
  if (tid < 16) grp[tid] = 0.f;
  float s_acc[4], s2_acc[4];
  #pragma unroll
  for (int p=0;p<4;p++){
    const int cc = (tid>>4) + p*16, tt = (tid&15)*4;
    const float4 v = *(const float4*)&src[((long)b*C + c0+cc)*8192 + t0+tt];
    tile[cc][tt+0]=v.x; tile[cc][tt+1]=v.y; tile[cc][tt+2]=v.z; tile[cc][tt+3]=v.w;
    s_acc[p]  = v.x+v.y+v.z+v.w;
    s2_acc[p] = v.x*v.x+v.y*v.y+v.z*v.z+v.w*v.w;
  }
  __syncthreads();
  // per-channel reduce within 16-lane groups (lanes 0-15,16-31,... share one channel)
  #pragma unroll
  for (int p=0;p<4;p++){
    float s = s_acc[p], s2 = s2_acc[p];
    #pragma unroll
    for (int m=1; m<16; m<<=1){ s += __shfl_xor(s, m); s2 += __shfl_xor(s2, m); }
    if ((tid&15)==0){
      const int gl = ((tid>>4) + p*16) >> chsh;
      atomicAdd(&grp[gl*2],   s);
      atomicAdd(&grp[gl*2+1], s2);
    }
  }
  #pragma unroll
  for (int p=0;p<4;p++){
    const int tt = (tid>>4) + p*16, c4 = (tid&15)*4;
    u16 rbi[4];
    #pragma unroll
    for (int j=0;j<4;j++) rbi[j] = f2b(tile[c4+j][tt]);
    ushort4 rv; rv.x=rbi[0]; rv.y=rbi[1]; rv.z=rbi[2]; rv.w=rbi[3];
    *(ushort4*)&dst[((long)b*8192 + t0+tt)*C + c0+c4] = rv;
  }
  __syncthreads();
  const int ngr = 64>>chsh;
  if (tid < ngr*2){
    atomicAdd(&stat[((b*32) + (c0>>chsh))*2 + tid], grp[tid]);
  }
}

// ---------------- MFMA GEMM: out[t,o] = sum_k A[t,k]*W[o,k] ----------------
// wsb/bsb: per-batch strides for folded weights/bias (0 for shared)
// TRANS: write fp32 directly in [B,256,T] layout (fuses the final transpose)
template<bool OUTB, bool BIAS, bool SILU, bool RES, bool STATS, bool SPLIT, bool TRANS>
__global__ __launch_bounds__(256,2) void k_gemm(
    const u16* __restrict__ A, const u16* __restrict__ W,
    float* __restrict__ outF, u16* __restrict__ outB,
    const float* __restrict__ bias, const u16* __restrict__ res,
    float* __restrict__ stat, int K, int O, long wsb, int bsb)
{
  __shared__ u16 As[128*64];
  __shared__ u16 Ws[128*64];
  __shared__ float sb[128][2];
  const int tid = threadIdx.x;
  const int wv = tid>>6, lane = tid&63;
  // XCD-chunked bijective swizzle (all grids have nwg % 8 == 0):
  // consecutive fid (round-robin across XCDs) -> contiguous tile chunks per XCD
  const int nwg = (int)(gridDim.x*gridDim.y);
  int fid = (int)(blockIdx.y*gridDim.x + blockIdx.x);
  fid = (fid&7)*(nwg>>3) + (fid>>3);
  const long t0 = (long)(fid / (int)gridDim.x)*128;
  const int o0 = (fid % (int)gridDim.x)*128;
  const int bb = (int)(t0>>13);
  const u16* Wp = W + (long)bb*wsb;
  const int wt = (wv>>1)*64, wo = (wv&1)*64;
  const int lr = lane>>3, lc = (lane&7)*8;
  f32x4 acc[4][4] = {};
  for (int kc = 0; kc < K; kc += 64){
    #pragma unroll
    for (int it = 0; it < 4; ++it){
      const int r = wv*32 + it*8;
      GLL(A + (t0 + r + lr)*(long)K + kc + lc, &As[r*64]);
      GLL(Wp + (long)(o0 + r + lr)*K + kc + lc, &Ws[r*64]);
    }
    __syncthreads();
    #pragma unroll
    for (int ks=0; ks<2; ++ks){
      const int kb = ks*32 + (lane>>4)*8;
      bf16x8 af[4], bfr[4];
      #pragma unroll
      for (int i=0;i<4;i++) af[i]  = *(const bf16x8*)&As[(wt + i*16 + (lane&15))*64 + kb];
      #pragma unroll
      for (int j=0;j<4;j++) bfr[j] = *(const bf16x8*)&Ws[(wo + j*16 + (lane&15))*64 + kb];
      #pragma unroll
      for (int i=0;i<4;i++)
        #pragma unroll
        for (int j=0;j<4;j++)
          acc[i][j] = __builtin_amdgcn_mfma_f32_16x16x32_bf16(af[i], bfr[j], acc[i][j], 0, 0, 0);
    }
    __syncthreads();
  }
  if (STATS){
    if (tid < 128){ sb[tid][0]=0.f; sb[tid][1]=0.f; }
    __syncthreads();
  }
  const int q = lane>>4, cc = lane&15;
  #pragma unroll
  for (int j=0;j<4;j++){
    const int o = o0 + wo + j*16 + cc;
    const float bv = BIAS ? bias[bsb*bb + o] : 0.f;
    float ts=0.f, ts2=0.f;
    #pragma unroll
    for (int i=0;i<4;i++){
      const long tb = t0 + wt + i*16 + q*4;
      if (TRANS){
        float vv[4];
        #pragma unroll
        for (int r=0;r<4;r++){
          float v = acc[i][j][r] + bv;
          if (SILU) v = v * (1.f/(1.f + __expf(-v)));
          if (RES) v += b2f(res[(tb + r)*(long)O + o]);
          vv[r] = v;
        }
        float4 v4; v4.x=vv[0]; v4.y=vv[1]; v4.z=vv[2]; v4.w=vv[3];
        *(float4*)&outF[(((tb>>13)*(long)O + o)<<13) + (tb&8191)] = v4;
      } else {
        #pragma unroll
        for (int r=0;r<4;r++){
          float v = acc[i][j][r] + bv;
          if (SILU) v = v * (1.f/(1.f + __expf(-v)));
          long idx;
          if (SPLIT) idx = ((long)(o>>8)<<24) + (tb + r)*256 + (o&255);
          else       idx = (tb + r)*(long)O + o;
          if (RES) v += b2f(res[idx]);
          if (STATS){ ts += v; ts2 += v*v; }
          if (OUTB) outB[idx] = f2b(v); else outF[idx] = v;
        }
      }
    }
    if (STATS){
      const int ol = wo + j*16 + cc;
      atomicAdd(&sb[ol][0], ts);
      atomicAdd(&sb[ol][1], ts2);
    }
  }
  if (STATS){
    __syncthreads();
    if (tid < 16){
      float u=0.f, u2=0.f;
      #pragma unroll
      for (int j2=0;j2<8;j2++){ u += sb[tid*8+j2][0]; u2 += sb[tid*8+j2][1]; }
      atomicAdd(&stat[(bb*32 + (o0>>3) + tid)*2],   u);
      atomicAdd(&stat[(bb*32 + (o0>>3) + tid)*2+1], u2);
    }
  }
}

// ---------------- ctx partials + per-block ksum partial; dense [65536,256] k/v inputs ----------------
__global__ __launch_bounds__(256,2) void k_ctx(const u16* __restrict__ kp, const u16* __restrict__ vp,
                                               float* __restrict__ part){
  const int tid = threadIdx.x;
  const int b = blockIdx.x >> 6, seg = blockIdx.x & 63;
  const int h = tid>>5, d = tid&31;
  __shared__ u16 kb[16][256];
  __shared__ float vf[16][260];
  float acc[32];
  #pragma unroll
  for (int e=0;e<32;e++) acc[e]=0.f;
  float ks = 0.f;
  const long rb = (long)b*8192 + seg*128;
  const int w = tid>>6, sub = tid&63;
  for (int tc=0; tc<128; tc+=16){
    #pragma unroll
    for (int p=0;p<4;p++){
      const int row = p*4 + w;
      const long rowbase = (rb + tc + row)*256;
      if (sub < 32){
        uint4 val = *(const uint4*)(kp + rowbase + sub*8);
        *(uint4*)&kb[row][sub*8] = val;
      } else {
        const int s2 = sub-32;
        uint4 val = *(const uint4*)(vp + rowbase + s2*8);
        const u16* vs = (const u16*)&val;
        float4 f0 = {b2f(vs[0]),b2f(vs[1]),b2f(vs[2]),b2f(vs[3])};
        float4 f1 = {b2f(vs[4]),b2f(vs[5]),b2f(vs[6]),b2f(vs[7])};
        *(float4*)&vf[row][s2*8] = f0;
        *(float4*)&vf[row][s2*8+4] = f1;
      }
    }
    __syncthreads();
    #pragma unroll
    for (int r=0;r<16;r++){
      const float kpv = __expf(b2f(kb[r][h*32+d]));
      ks += kpv;
      #pragma unroll
      for (int e4=0;e4<8;e4++){
        const float4 v4 = *(const float4*)&vf[r][h*32+e4*4];
        acc[e4*4+0] += kpv*v4.x; acc[e4*4+1] += kpv*v4.y;
        acc[e4*4+2] += kpv*v4.z; acc[e4*4+3] += kpv*v4.w;
      }
    }
    __syncthreads();
  }
  float* pb = part + (long)blockIdx.x*8448;
  #pragma unroll
  for (int e=0;e<32;e++) pb[e*256 + tid] = acc[e];
  pb[8192 + tid] = ks;
}

// ---------------- reduce ctx partials + ksum partials ----------------
__global__ void k_ctxred(const float* __restrict__ part, float* __restrict__ ctx,
                         float* __restrict__ ksumF){
  if (blockIdx.x >= 256){
    const int j = (blockIdx.x-256)*256 + threadIdx.x;
    #pragma unroll
    for (int q=0;q<4;q++){
      const int idx = j*4+q;
      const int b = idx>>8, cch = idx&255;
      float s=0.f;
      for (int g=0; g<64; g++) s += part[((long)(b*64+g))*8448 + 8192 + cch];
      ksumF[idx] = s;
    }
    return;
  }
  const int i = blockIdx.x*256 + threadIdx.x;
  const int b = i>>13, r = i&8191;
  float s=0.f;
  for (int g=0; g<64; g++) s += part[((long)(b*64+g))*8448 + r];
  ctx[i] = s;
}

// ---------------- attn out: q-softmax contraction against ctx/ksum; q dense [65536,256] ----
__global__ void k_attnout(const u16* __restrict__ q, const float* __restrict__ ctx,
                          const float* __restrict__ ksumF, u16* __restrict__ out){
  const int b = blockIdx.x >> 8, t0 = (blockIdx.x & 255)*32;
  __shared__ float cs[8512];   // [h][d][e] strides 1064/33/1
  for (int i=threadIdx.x; i<8192; i+=256){
    const int e=i>>8, cch=i&255;
    cs[(cch>>5)*1064 + (cch&31)*33 + e] = ctx[(b<<13) + i] / ksumF[b*256 + cch];
  }
  __syncthreads();
  const int t = t0 + (threadIdx.x>>3), h = threadIdx.x&7;
  const u16* qp = q + ((long)b*8192 + t)*256 + h*32;
  uint4 qv[4];
  #pragma unroll
  for (int j=0;j<4;j++) qv[j] = ((const uint4*)qp)[j];
  const u16* qs = (const u16*)qv;
  float qe[32]; float ssum = 0.f;
  #pragma unroll
  for (int dd=0; dd<32; dd++){ qe[dd] = __expf(b2f(qs[dd])); ssum += qe[dd]; }
  const float inv = 0.17677669529663687f / ssum;
  float o[32];
  #pragma unroll
  for (int e=0;e<32;e++) o[e]=0.f;
  const float* ch = &cs[h*1064];
  #pragma unroll
  for (int dd=0; dd<32; dd++){
    const float w = qe[dd]*inv;
    #pragma unroll
    for (int e=0;e<32;e++) o[e] += w * ch[dd*33+e];
  }
  u16 ob[32];
  #pragma unroll
  for (int e=0;e<32;e++) ob[e] = f2b(o[e]);
  uint4* op = (uint4*)(out + ((long)b*8192 + t)*256 + h*32);
  const uint4* obv = (const uint4*)ob;
  #pragma unroll
  for (int j=0;j<4;j++) op[j] = obv[j];
}

// ---------------- x_new = GN(conv)*g+b + x (bf16 residual, in-place) + stats of x_new ----------------
__global__ void k_gnres(const u16* __restrict__ conv, u16* __restrict__ xr,
                        const float* __restrict__ sums_in, float* __restrict__ sums_out,
                        const float* __restrict__ g, const float* __restrict__ bt){
  const int blk = blockIdx.x;
  const int b = blk>>7;
  const long base = (long)blk*4096;
  const int tid = threadIdx.x;
  const int c0 = (tid<<2)&255;
  const int gr = c0>>3;
  const float s = sums_in[(b*32+gr)*2], s2 = sums_in[(b*32+gr)*2+1];
  const float mu = s*(1.f/65536.f);
  const float rs = rsqrtf(s2*(1.f/65536.f) - mu*mu + 1e-5f);
  float gg[4], bb[4];
  #pragma unroll
  for (int j=0;j<4;j++){ gg[j] = g[c0+j]*rs; bb[j] = bt[c0+j] - mu*gg[j]; }
  float ts=0.f, ts2=0.f;
  for (int it=0; it<16; ++it){
    const long i4 = base + it*256 + tid;
    ushort4 cv = ((const ushort4*)conv)[i4];
    ushort4 rv = ((const ushort4*)xr)[i4];
    float ov[4];
    const float ci[4] = {b2f(cv.x),b2f(cv.y),b2f(cv.z),b2f(cv.w)};
    const float ri[4] = {b2f(rv.x),b2f(rv.y),b2f(rv.z),b2f(rv.w)};
    #pragma unroll
    for (int j=0;j<4;j++){
      ov[j] = ci[j]*gg[j] + bb[j] + ri[j];
      ts += ov[j]; ts2 += ov[j]*ov[j];
    }
    ushort4 o4; o4.x=f2b(ov[0]); o4.y=f2b(ov[1]); o4.z=f2b(ov[2]); o4.w=f2b(ov[3]);
    ((ushort4*)xr)[i4] = o4;
  }
  __shared__ float grp[32][2];
  if (tid<32){ grp[tid][0]=0.f; grp[tid][1]=0.f; }
  __syncthreads();
  atomicAdd(&grp[gr][0], ts);
  atomicAdd(&grp[gr][1], ts2);
  __syncthreads();
  if (tid<32){
    atomicAdd(&sums_out[(b*32+tid)*2],   grp[tid][0]);
    atomicAdd(&sums_out[(b*32+tid)*2+1], grp[tid][1]);
  }
}

extern "C" void kernel_launch(void* const* d_in, const int* in_sizes, int n_in,
                              void* d_out, int out_size, void* d_ws, size_t ws_size,
                              hipStream_t stream){
  (void)in_sizes; (void)n_in; (void)out_size; (void)ws_size;
  const float* x   = (const float*)d_in[0];
  const float* c   = (const float*)d_in[1];
  const float* W_qkv=(const float*)d_in[2];
  const float* W_so =(const float*)d_in[3];
  const float* b_so =(const float*)d_in[4];
  const float* sa_g =(const float*)d_in[5];
  const float* sa_b =(const float*)d_in[6];
  const float* W_cq =(const float*)d_in[7];
  const float* W_ckv=(const float*)d_in[8];
  const float* W_co =(const float*)d_in[9];
  const float* b_co =(const float*)d_in[10];
  const float* ca_g =(const float*)d_in[11];
  const float* ca_b =(const float*)d_in[12];
  const float* W_m1 =(const float*)d_in[13];
  const float* b_m1 =(const float*)d_in[14];
  const float* W_m2 =(const float*)d_in[15];
  const float* b_m2 =(const float*)d_in[16];
  const float* nm_g =(const float*)d_in[17];
  const float* nm_b =(const float*)d_in[18];
  const float* nm1_g=(const float*)d_in[19];
  const float* nm1_b=(const float*)d_in[20];
  const float* nm2_g=(const float*)d_in[21];
  const float* nm2_b=(const float*)d_in[22];
  const float* nm3_g=(const float*)d_in[23];
  const float* nm3_b=(const float*)d_in[24];
  float* out = (float*)d_out;

  char* ws = (char*)d_ws;
  const size_t MB = 1024ull*1024ull;
  // non-folded weights (bf16)
  u16* wSO = (u16*)ws;                 // 65536
  u16* wCO = wSO + 65536;              // 65536
  u16* wM2 = wCO + 65536;              // 163840
  // stats
  float* stats = (float*)(ws + 1*MB);
  float* xstat = stats;                // 512
  float* cstat = stats + 512;          // 512
  float* so_sum= stats + 1024;
  float* x1_sum= stats + 1536;
  float* co_sum= stats + 2048;
  float* x2_sum= stats + 2560;
  float* ksumF = stats + 3072;         // 2048
  float* ctxb  = stats + 8192;         // 65536
  // folded biases (fp32)
  float* bQKV = (float*)(ws + 2*MB);   // 8*768
  float* bCKV = bQKV + 6144;           // 8*512
  float* bCQ  = bCKV + 4096;           // 8*256
  float* bM1  = bCQ + 2048;            // 8*640
  // folded per-batch weights (bf16)
  u16* wQKVb = (u16*)(ws + 3*MB);      // 8*768*256 = 3 MB
  u16* wCKVb = (u16*)(ws + 6*MB);      // 8*512*512 = 4 MB
  u16* wCQb  = (u16*)(ws + 10*MB);     // 8*256*256 = 1 MB
  u16* wM1b  = (u16*)(ws + 11*MB);     // 8*640*256 = 2.5 MB
  // streams
  u16*   xT    = (u16*)(ws + 16*MB);   // [65536,256] bf16 raw residual (in-place)
  u16*   cT    = (u16*)(ws + 48*MB);   // [65536,512] bf16 raw transposed c
  float* part  = (float*)(ws + 112*MB);// [512][8448] fp32 partials
  u16*   qkvb  = (u16*)(ws + 136*MB);  // 3 x 2^24 bf16 (q,k,v; reused: cross-q, mlp hidden)
  u16*   kvb   = (u16*)(ws + 232*MB);  // 2 x 2^24 bf16 cross k,v (aliased convb)
  u16*   convb = kvb;
  u16*   attno = (u16*)(ws + 296*MB);  // [65536,256] bf16
  const long SEG = 1L<<24;

  k_init<<<1153,256,0,stream>>>(W_so, W_co, W_m2, wSO, stats);

  // ---- transpose + fused GN raw sums (x and c in one launch) ----
  k_transs<<<dim3(128,12,8),256,0,stream>>>(x, c, xT, cT, xstat, cstat);

  // ---- stage 1: self linear attention ----
  k_fold2<<<dim3(1280,8),256,0,stream>>>(W_qkv, nm_g, nm_b, xstat, wQKVb, bQKV, 768, 256, 3, 1.f/65536.f,
                                         W_ckv, nm3_g, nm3_b, cstat, wCKVb, bCKV, 512, 512, 4, 1.f/131072.f);
  k_gemm<true,true,false,false,false,true,false><<<dim3(6,512),256,0,stream>>>(xT, wQKVb, nullptr, qkvb, bQKV, nullptr, nullptr, 256, 768, 196608, 768);
  k_ctx<<<512,256,0,stream>>>(qkvb+SEG, qkvb+2*SEG, part);
  k_ctxred<<<258,256,0,stream>>>(part, ctxb, ksumF);
  k_attnout<<<2048,256,0,stream>>>(qkvb, ctxb, ksumF, attno);
  k_gemm<true,true,false,false,true,false,false><<<dim3(2,512),256,0,stream>>>(attno, wSO, nullptr, convb, b_so, nullptr, so_sum, 256, 256, 0, 0);
  k_gnres<<<1024,256,0,stream>>>(convb, xT, so_sum, x1_sum, sa_g, sa_b);

  // ---- stage 2: cross linear attention ----
  k_fold<<<dim3(256,8),256,0,stream>>>(W_cq, nm1_g, nm1_b, nullptr, x1_sum, wCQb, bCQ, 256, 256, 3, 1.f/65536.f);
  k_gemm<true,true,false,false,false,false,false><<<dim3(2,512),256,0,stream>>>(xT, wCQb, nullptr, qkvb, bCQ, nullptr, nullptr, 256, 256, 65536, 256);
  k_gemm<true,true,false,false,false,true,false><<<dim3(4,512),256,0,stream>>>(cT, wCKVb, nullptr, kvb, bCKV, nullptr, nullptr, 512, 512, 262144, 512);
  k_ctx<<<512,256,0,stream>>>(kvb, kvb+SEG, part);
  k_ctxred<<<258,256,0,stream>>>(part, ctxb, ksumF);
  k_attnout<<<2048,256,0,stream>>>(qkvb, ctxb, ksumF, attno);
  k_gemm<true,true,false,false,true,false,false><<<dim3(2,512),256,0,stream>>>(attno, wCO, nullptr, convb, b_co, nullptr, co_sum, 256, 256, 0, 0);
  k_gnres<<<1024,256,0,stream>>>(convb, xT, co_sum, x2_sum, ca_g, ca_b);

  // ---- stage 3: SiLU MLP ----
  k_fold<<<dim3(640,8),256,0,stream>>>(W_m1, nm2_g, nm2_b, b_m1, x2_sum, wM1b, bM1, 640, 256, 3, 1.f/65536.f);
  k_gemm<true,true,true,false,false,false,false><<<dim3(5,512),256,0,stream>>>(xT, wM1b, nullptr, qkvb, bM1, nullptr, nullptr, 256, 640, 163840, 640);
  // M2: fp32 output written directly transposed to [B,256,T] (k_final fused away)
  k_gemm<false,true,false,true,false,false,true><<<dim3(2,512),256,0,stream>>>(qkvb, wM2, out, nullptr, b_m2, xT, nullptr, 640, 256, 0, 0);
}

// Round 4
// 872.460 us; speedup vs baseline: 1.1171x; 1.0011x over previous
//
#include <hip/hip_runtime.h>
#include <cmath>

typedef unsigned short u16;
typedef __attribute__((ext_vector_type(8))) __bf16 bf16x8;
typedef __attribute__((ext_vector_type(4))) float f32x4;

#define DEV static __device__ __forceinline__

DEV float b2f(u16 u){ union{unsigned i; float f;} v; v.i=((unsigned)u)<<16; return v.f; }
DEV u16 f2b(float f){ union{float f; unsigned i;} v; v.f=f; unsigned r = v.i + 0x7FFFu + ((v.i>>16)&1u); return (u16)(r>>16); }

#define GLL(g,l) __builtin_amdgcn_global_load_lds((const __attribute__((address_space(1))) void*)(g), (__attribute__((address_space(3))) void*)(l), 16, 0, 0)

// ---------------- init: convert W_so|W_co|W_m2 to bf16 + zero stats ----------------
__global__ void k_init(const float* __restrict__ s0,const float* __restrict__ s1,
                       const float* __restrict__ s2, u16* __restrict__ d,
                       float* __restrict__ stats){
  const int bid = blockIdx.x;
  if (bid == 1152){
    #pragma unroll
    for (int j=0;j<12;j++){ const int idx=j*256+threadIdx.x; if (idx<3072) stats[idx]=0.f; }
    return;
  }
  const int i = bid*256 + threadIdx.x;
  const float* s; int off;
  if      (i < 65536){ s=s0; off=0; }
  else if (i < 131072){ s=s1; off=65536; }
  else                { s=s2; off=131072; }
  d[i] = f2b(s[i-off]);
}

// ---------------- GN->conv fold: per-batch weights + bias ----------------
// Wb[b][o][k] = W[o][k]*g[k]*rs[b,gr(k)];  biasb[b][o] = base[o] + sum_k W[o][k]*(beta[k]-mu*rs*g[k])
DEV void fold_body(const float* W, const float* g, const float* beta, const float* base,
                   const float* stats, u16* Wb, float* biasb, int O, int K, int chsh,
                   float inv_n, int o, int b){
  const int tid = threadIdx.x;
  float bp = 0.f;
  for (int k = tid; k < K; k += 256){
    const int gr = k >> chsh;
    const float s = stats[(b*32+gr)*2], s2 = stats[(b*32+gr)*2+1];
    const float mu = s*inv_n;
    const float rs = rsqrtf(s2*inv_n - mu*mu + 1e-5f);
    const float w = W[(long)o*K + k];
    const float gg = g[k]*rs;
    Wb[((long)b*O + o)*K + k] = f2b(w*gg);
    bp += w*(beta[k] - mu*gg);
  }
  __shared__ float red[256];
  red[tid] = bp; __syncthreads();
  for (int off=128; off>0; off>>=1){ if (tid<off) red[tid]+=red[tid+off]; __syncthreads(); }
  if (tid==0) biasb[b*O+o] = red[0] + (base ? base[o] : 0.f);
}

__global__ void k_fold(const float* __restrict__ W, const float* __restrict__ g,
                       const float* __restrict__ beta, const float* __restrict__ base,
                       const float* __restrict__ stats, u16* __restrict__ Wb,
                       float* __restrict__ biasb, int O, int K, int chsh, float inv_n){
  fold_body(W,g,beta,base,stats,Wb,biasb,O,K,chsh,inv_n,blockIdx.x,blockIdx.y);
}

// merged fold for QKV (O1 rows) + CKV (O2 rows)
__global__ void k_fold2(const float* __restrict__ W1, const float* __restrict__ g1,
                        const float* __restrict__ be1, const float* __restrict__ st1,
                        u16* __restrict__ Wb1, float* __restrict__ bb1, int O1, int K1, int chsh1, float inv1,
                        const float* __restrict__ W2, const float* __restrict__ g2,
                        const float* __restrict__ be2, const float* __restrict__ st2,
                        u16* __restrict__ Wb2, float* __restrict__ bb2, int O2, int K2, int chsh2, float inv2){
  const int o = blockIdx.x, b = blockIdx.y;
  if (o < O1) fold_body(W1,g1,be1,nullptr,st1,Wb1,bb1,O1,K1,chsh1,inv1,o,b);
  else        fold_body(W2,g2,be2,nullptr,st2,Wb2,bb2,O2,K2,chsh2,inv2,o-O1,b);
}

// ---------------- transpose [B,C,T] -> [B,T,C] raw bf16 + fused GN raw sums (x and c merged) ----
// Each block: 64 channels x 256 t, 4 tiles pipelined (loads for tile p+1 issued
// during the store phase of tile p; registers carry across the barrier).
__global__ void k_transs(const float* __restrict__ xsrc, const float* __restrict__ csrc,
                         u16* __restrict__ xdst, u16* __restrict__ cdst,
                         float* __restrict__ xstat, float* __restrict__ cstat){
  const int b = blockIdx.z;
  const int gy = blockIdx.y;
  const float* src; u16* dst; float* stat; int C, chsh, c0;
  if (gy < 4){ src=xsrc; dst=xdst; stat=xstat; C=256; chsh=3; c0=gy*64; }
  else       { src=csrc; dst=cdst; stat=cstat; C=512; chsh=4; c0=(gy-4)*64; }
  const int tsup = blockIdx.x*256;
  const int tid = threadIdx.x;
  __shared__ float tile[64][65];
  __shared__ float grp[16];
  if (tid < 16) grp[tid] = 0.f;
  const int ccb = tid>>4, ttl = (tid&15)*4;      // load-side coords
  const int ttr = tid>>4, c4 = (tid&15)*4;       // store-side coords
  const long srow = (long)b*C + c0;
  float s_acc[4]={0.f,0.f,0.f,0.f}, s2_acc[4]={0.f,0.f,0.f,0.f};
  float4 cur[4], nxt[4];
  #pragma unroll
  for (int p=0;p<4;p++)
    cur[p] = *(const float4*)&src[(srow + ccb + p*16)*8192 + tsup + ttl];
  for (int q4=0; q4<4; ++q4){
    const int t0 = tsup + q4*64;
    #pragma unroll
    for (int p=0;p<4;p++){
      const float4 v = cur[p];
      const int cc = ccb + p*16;
      tile[cc][ttl+0]=v.x; tile[cc][ttl+1]=v.y; tile[cc][ttl+2]=v.z; tile[cc][ttl+3]=v.w;
      s_acc[p]  += v.x+v.y+v.z+v.w;
      s2_acc[p] += v.x*v.x+v.y*v.y+v.z*v.z+v.w*v.w;
    }
    __syncthreads();
    if (q4 < 3){
      #pragma unroll
      for (int p=0;p<4;p++)
        nxt[p] = *(const float4*)&src[(srow + ccb + p*16)*8192 + t0 + 64 + ttl];
    }
    #pragma unroll
    for (int p=0;p<4;p++){
      const int tt = ttr + p*16;
      u16 rbi[4];
      #pragma unroll
      for (int j=0;j<4;j++) rbi[j] = f2b(tile[c4+j][tt]);
      ushort4 rv; rv.x=rbi[0]; rv.y=rbi[1]; rv.z=rbi[2]; rv.w=rbi[3];
      *(ushort4*)&dst[((long)b*8192 + t0+tt)*C + c0+c4] = rv;
    }
    __syncthreads();
    if (q4 < 3){
      #pragma unroll
      for (int p=0;p<4;p++) cur[p] = nxt[p];
    }
  }
  // single stats-reduce phase per block (per-channel 16-lane shuffle reduce)
  #pragma unroll
  for (int p=0;p<4;p++){
    float s = s_acc[p], s2 = s2_acc[p];
    #pragma unroll
    for (int m=1; m<16; m<<=1){ s += __shfl_xor(s, m); s2 += __shfl_xor(s2, m); }
    if ((tid&15)==0){
      const int gl = (ccb + p*16) >> chsh;
      atomicAdd(&grp[gl*2],   s);
      atomicAdd(&grp[gl*2+1], s2);
    }
  }
  __syncthreads();
  const int ngr = 64>>chsh;
  if (tid < ngr*2){
    atomicAdd(&stat[((b*32) + (c0>>chsh))*2 + tid], grp[tid]);
  }
}

// ---------------- MFMA GEMM: out[t,o] = sum_k A[t,k]*W[o,k] ----------------
// wsb/bsb: per-batch strides for folded weights/bias (0 for shared)
// TRANS: write fp32 directly in [B,256,T] layout (fuses the final transpose)
template<bool OUTB, bool BIAS, bool SILU, bool RES, bool STATS, bool SPLIT, bool TRANS>
__global__ __launch_bounds__(256,2) void k_gemm(
    const u16* __restrict__ A, const u16* __restrict__ W,
    float* __restrict__ outF, u16* __restrict__ outB,
    const float* __restrict__ bias, const u16* __restrict__ res,
    float* __restrict__ stat, int K, int O, long wsb, int bsb)
{
  __shared__ u16 As[128*64];
  __shared__ u16 Ws[128*64];
  __shared__ float sb[128][2];
  const int tid = threadIdx.x;
  const int wv = tid>>6, lane = tid&63;
  // XCD-chunked bijective swizzle (all grids have nwg % 8 == 0):
  // consecutive fid (round-robin across XCDs) -> contiguous tile chunks per XCD
  const int nwg = (int)(gridDim.x*gridDim.y);
  int fid = (int)(blockIdx.y*gridDim.x + blockIdx.x);
  fid = (fid&7)*(nwg>>3) + (fid>>3);
  const long t0 = (long)(fid / (int)gridDim.x)*128;
  const int o0 = (fid % (int)gridDim.x)*128;
  const int bb = (int)(t0>>13);
  const u16* Wp = W + (long)bb*wsb;
  const int wt = (wv>>1)*64, wo = (wv&1)*64;
  const int lr = lane>>3, lc = (lane&7)*8;
  f32x4 acc[4][4] = {};
  for (int kc = 0; kc < K; kc += 64){
    #pragma unroll
    for (int it = 0; it < 4; ++it){
      const int r = wv*32 + it*8;
      GLL(A + (t0 + r + lr)*(long)K + kc + lc, &As[r*64]);
      GLL(Wp + (long)(o0 + r + lr)*K + kc + lc, &Ws[r*64]);
    }
    __syncthreads();
    #pragma unroll
    for (int ks=0; ks<2; ++ks){
      const int kb = ks*32 + (lane>>4)*8;
      bf16x8 af[4], bfr[4];
      #pragma unroll
      for (int i=0;i<4;i++) af[i]  = *(const bf16x8*)&As[(wt + i*16 + (lane&15))*64 + kb];
      #pragma unroll
      for (int j=0;j<4;j++) bfr[j] = *(const bf16x8*)&Ws[(wo + j*16 + (lane&15))*64 + kb];
      #pragma unroll
      for (int i=0;i<4;i++)
        #pragma unroll
        for (int j=0;j<4;j++)
          acc[i][j] = __builtin_amdgcn_mfma_f32_16x16x32_bf16(af[i], bfr[j], acc[i][j], 0, 0, 0);
    }
    __syncthreads();
  }
  if (STATS){
    if (tid < 128){ sb[tid][0]=0.f; sb[tid][1]=0.f; }
    __syncthreads();
  }
  const int q = lane>>4, cc = lane&15;
  #pragma unroll
  for (int j=0;j<4;j++){
    const int o = o0 + wo + j*16 + cc;
    const float bv = BIAS ? bias[bsb*bb + o] : 0.f;
    float ts=0.f, ts2=0.f;
    #pragma unroll
    for (int i=0;i<4;i++){
      const long tb = t0 + wt + i*16 + q*4;
      if (TRANS){
        float vv[4];
        #pragma unroll
        for (int r=0;r<4;r++){
          float v = acc[i][j][r] + bv;
          if (SILU) v = v * (1.f/(1.f + __expf(-v)));
          if (RES) v += b2f(res[(tb + r)*(long)O + o]);
          vv[r] = v;
        }
        float4 v4; v4.x=vv[0]; v4.y=vv[1]; v4.z=vv[2]; v4.w=vv[3];
        *(float4*)&outF[(((tb>>13)*(long)O + o)<<13) + (tb&8191)] = v4;
      } else {
        #pragma unroll
        for (int r=0;r<4;r++){
          float v = acc[i][j][r] + bv;
          if (SILU) v = v * (1.f/(1.f + __expf(-v)));
          long idx;
          if (SPLIT) idx = ((long)(o>>8)<<24) + (tb + r)*256 + (o&255);
          else       idx = (tb + r)*(long)O + o;
          if (RES) v += b2f(res[idx]);
          if (STATS){ ts += v; ts2 += v*v; }
          if (OUTB) outB[idx] = f2b(v); else outF[idx] = v;
        }
      }
    }
    if (STATS){
      const int ol = wo + j*16 + cc;
      atomicAdd(&sb[ol][0], ts);
      atomicAdd(&sb[ol][1], ts2);
    }
  }
  if (STATS){
    __syncthreads();
    if (tid < 16){
      float u=0.f, u2=0.f;
      #pragma unroll
      for (int j2=0;j2<8;j2++){ u += sb[tid*8+j2][0]; u2 += sb[tid*8+j2][1]; }
      atomicAdd(&stat[(bb*32 + (o0>>3) + tid)*2],   u);
      atomicAdd(&stat[(bb*32 + (o0>>3) + tid)*2+1], u2);
    }
  }
}

// ---------------- ctx partials + per-block ksum partial; dense [65536,256] k/v inputs ----------------
__global__ __launch_bounds__(256,2) void k_ctx(const u16* __restrict__ kp, const u16* __restrict__ vp,
                                               float* __restrict__ part){
  const int tid = threadIdx.x;
  const int b = blockIdx.x >> 6, seg = blockIdx.x & 63;
  const int h = tid>>5, d = tid&31;
  __shared__ u16 kb[16][256];
  __shared__ float vf[16][260];
  float acc[32];
  #pragma unroll
  for (int e=0;e<32;e++) acc[e]=0.f;
  float ks = 0.f;
  const long rb = (long)b*8192 + seg*128;
  const int w = tid>>6, sub = tid&63;
  for (int tc=0; tc<128; tc+=16){
    #pragma unroll
    for (int p=0;p<4;p++){
      const int row = p*4 + w;
      const long rowbase = (rb + tc + row)*256;
      if (sub < 32){
        uint4 val = *(const uint4*)(kp + rowbase + sub*8);
        *(uint4*)&kb[row][sub*8] = val;
      } else {
        const int s2 = sub-32;
        uint4 val = *(const uint4*)(vp + rowbase + s2*8);
        const u16* vs = (const u16*)&val;
        float4 f0 = {b2f(vs[0]),b2f(vs[1]),b2f(vs[2]),b2f(vs[3])};
        float4 f1 = {b2f(vs[4]),b2f(vs[5]),b2f(vs[6]),b2f(vs[7])};
        *(float4*)&vf[row][s2*8] = f0;
        *(float4*)&vf[row][s2*8+4] = f1;
      }
    }
    __syncthreads();
    #pragma unroll
    for (int r=0;r<16;r++){
      const float kpv = __expf(b2f(kb[r][h*32+d]));
      ks += kpv;
      #pragma unroll
      for (int e4=0;e4<8;e4++){
        const float4 v4 = *(const float4*)&vf[r][h*32+e4*4];
        acc[e4*4+0] += kpv*v4.x; acc[e4*4+1] += kpv*v4.y;
        acc[e4*4+2] += kpv*v4.z; acc[e4*4+3] += kpv*v4.w;
      }
    }
    __syncthreads();
  }
  float* pb = part + (long)blockIdx.x*8448;
  #pragma unroll
  for (int e=0;e<32;e++) pb[e*256 + tid] = acc[e];
  pb[8192 + tid] = ks;
}

// ---------------- reduce ctx partials + ksum partials ----------------
__global__ void k_ctxred(const float* __restrict__ part, float* __restrict__ ctx,
                         float* __restrict__ ksumF){
  if (blockIdx.x >= 256){
    const int j = (blockIdx.x-256)*256 + threadIdx.x;
    #pragma unroll
    for (int q=0;q<4;q++){
      const int idx = j*4+q;
      const int b = idx>>8, cch = idx&255;
      float s=0.f;
      for (int g=0; g<64; g++) s += part[((long)(b*64+g))*8448 + 8192 + cch];
      ksumF[idx] = s;
    }
    return;
  }
  const int i = blockIdx.x*256 + threadIdx.x;
  const int b = i>>13, r = i&8191;
  float s=0.f;
  for (int g=0; g<64; g++) s += part[((long)(b*64+g))*8448 + r];
  ctx[i] = s;
}

// ---------------- attn out: q-softmax contraction against ctx/ksum; q dense [65536,256] ----
__global__ void k_attnout(const u16* __restrict__ q, const float* __restrict__ ctx,
                          const float* __restrict__ ksumF, u16* __restrict__ out){
  const int b = blockIdx.x >> 8, t0 = (blockIdx.x & 255)*32;
  __shared__ float cs[8512];   // [h][d][e] strides 1064/33/1
  for (int i=threadIdx.x; i<8192; i+=256){
    const int e=i>>8, cch=i&255;
    cs[(cch>>5)*1064 + (cch&31)*33 + e] = ctx[(b<<13) + i] / ksumF[b*256 + cch];
  }
  __syncthreads();
  const int t = t0 + (threadIdx.x>>3), h = threadIdx.x&7;
  const u16* qp = q + ((long)b*8192 + t)*256 + h*32;
  uint4 qv[4];
  #pragma unroll
  for (int j=0;j<4;j++) qv[j] = ((const uint4*)qp)[j];
  const u16* qs = (const u16*)qv;
  float qe[32]; float ssum = 0.f;
  #pragma unroll
  for (int dd=0; dd<32; dd++){ qe[dd] = __expf(b2f(qs[dd])); ssum += qe[dd]; }
  const float inv = 0.17677669529663687f / ssum;
  float o[32];
  #pragma unroll
  for (int e=0;e<32;e++) o[e]=0.f;
  const float* ch = &cs[h*1064];
  #pragma unroll
  for (int dd=0; dd<32; dd++){
    const float w = qe[dd]*inv;
    #pragma unroll
    for (int e=0;e<32;e++) o[e] += w * ch[dd*33+e];
  }
  u16 ob[32];
  #pragma unroll
  for (int e=0;e<32;e++) ob[e] = f2b(o[e]);
  uint4* op = (uint4*)(out + ((long)b*8192 + t)*256 + h*32);
  const uint4* obv = (const uint4*)ob;
  #pragma unroll
  for (int j=0;j<4;j++) op[j] = obv[j];
}

// ---------------- x_new = GN(conv)*g+b + x (bf16 residual, in-place) + stats of x_new ----------------
__global__ void k_gnres(const u16* __restrict__ conv, u16* __restrict__ xr,
                        const float* __restrict__ sums_in, float* __restrict__ sums_out,
                        const float* __restrict__ g, const float* __restrict__ bt){
  const int blk = blockIdx.x;
  const int b = blk>>7;
  const long base = (long)blk*4096;
  const int tid = threadIdx.x;
  const int c0 = (tid<<2)&255;
  const int gr = c0>>3;
  const float s = sums_in[(b*32+gr)*2], s2 = sums_in[(b*32+gr)*2+1];
  const float mu = s*(1.f/65536.f);
  const float rs = rsqrtf(s2*(1.f/65536.f) - mu*mu + 1e-5f);
  float gg[4], bb[4];
  #pragma unroll
  for (int j=0;j<4;j++){ gg[j] = g[c0+j]*rs; bb[j] = bt[c0+j] - mu*gg[j]; }
  float ts=0.f, ts2=0.f;
  for (int it=0; it<16; ++it){
    const long i4 = base + it*256 + tid;
    ushort4 cv = ((const ushort4*)conv)[i4];
    ushort4 rv = ((const ushort4*)xr)[i4];
    float ov[4];
    const float ci[4] = {b2f(cv.x),b2f(cv.y),b2f(cv.z),b2f(cv.w)};
    const float ri[4] = {b2f(rv.x),b2f(rv.y),b2f(rv.z),b2f(rv.w)};
    #pragma unroll
    for (int j=0;j<4;j++){
      ov[j] = ci[j]*gg[j] + bb[j] + ri[j];
      ts += ov[j]; ts2 += ov[j]*ov[j];
    }
    ushort4 o4; o4.x=f2b(ov[0]); o4.y=f2b(ov[1]); o4.z=f2b(ov[2]); o4.w=f2b(ov[3]);
    ((ushort4*)xr)[i4] = o4;
  }
  __shared__ float grp[32][2];
  if (tid<32){ grp[tid][0]=0.f; grp[tid][1]=0.f; }
  __syncthreads();
  atomicAdd(&grp[gr][0], ts);
  atomicAdd(&grp[gr][1], ts2);
  __syncthreads();
  if (tid<32){
    atomicAdd(&sums_out[(b*32+tid)*2],   grp[tid][0]);
    atomicAdd(&sums_out[(b*32+tid)*2+1], grp[tid][1]);
  }
}

extern "C" void kernel_launch(void* const* d_in, const int* in_sizes, int n_in,
                              void* d_out, int out_size, void* d_ws, size_t ws_size,
                              hipStream_t stream){
  (void)in_sizes; (void)n_in; (void)out_size; (void)ws_size;
  const float* x   = (const float*)d_in[0];
  const float* c   = (const float*)d_in[1];
  const float* W_qkv=(const float*)d_in[2];
  const float* W_so =(const float*)d_in[3];
  const float* b_so =(const float*)d_in[4];
  const float* sa_g =(const float*)d_in[5];
  const float* sa_b =(const float*)d_in[6];
  const float* W_cq =(const float*)d_in[7];
  const float* W_ckv=(const float*)d_in[8];
  const float* W_co =(const float*)d_in[9];
  const float* b_co =(const float*)d_in[10];
  const float* ca_g =(const float*)d_in[11];
  const float* ca_b =(const float*)d_in[12];
  const float* W_m1 =(const float*)d_in[13];
  const float* b_m1 =(const float*)d_in[14];
  const float* W_m2 =(const float*)d_in[15];
  const float* b_m2 =(const float*)d_in[16];
  const float* nm_g =(const float*)d_in[17];
  const float* nm_b =(const float*)d_in[18];
  const float* nm1_g=(const float*)d_in[19];
  const float* nm1_b=(const float*)d_in[20];
  const float* nm2_g=(const float*)d_in[21];
  const float* nm2_b=(const float*)d_in[22];
  const float* nm3_g=(const float*)d_in[23];
  const float* nm3_b=(const float*)d_in[24];
  float* out = (float*)d_out;

  char* ws = (char*)d_ws;
  const size_t MB = 1024ull*1024ull;
  // non-folded weights (bf16)
  u16* wSO = (u16*)ws;                 // 65536
  u16* wCO = wSO + 65536;              // 65536
  u16* wM2 = wCO + 65536;              // 163840
  // stats
  float* stats = (float*)(ws + 1*MB);
  float* xstat = stats;                // 512
  float* cstat = stats + 512;          // 512
  float* so_sum= stats + 1024;
  float* x1_sum= stats + 1536;
  float* co_sum= stats + 2048;
  float* x2_sum= stats + 2560;
  float* ksumF = stats + 3072;         // 2048
  float* ctxb  = stats + 8192;         // 65536
  // folded biases (fp32)
  float* bQKV = (float*)(ws + 2*MB);   // 8*768
  float* bCKV = bQKV + 6144;           // 8*512
  float* bCQ  = bCKV + 4096;           // 8*256
  float* bM1  = bCQ + 2048;            // 8*640
  // folded per-batch weights (bf16)
  u16* wQKVb = (u16*)(ws + 3*MB);      // 8*768*256 = 3 MB
  u16* wCKVb = (u16*)(ws + 6*MB);      // 8*512*512 = 4 MB
  u16* wCQb  = (u16*)(ws + 10*MB);     // 8*256*256 = 1 MB
  u16* wM1b  = (u16*)(ws + 11*MB);     // 8*640*256 = 2.5 MB
  // streams
  u16*   xT    = (u16*)(ws + 16*MB);   // [65536,256] bf16 raw residual (in-place)
  u16*   cT    = (u16*)(ws + 48*MB);   // [65536,512] bf16 raw transposed c
  float* part  = (float*)(ws + 112*MB);// [512][8448] fp32 partials
  u16*   qkvb  = (u16*)(ws + 136*MB);  // 3 x 2^24 bf16 (q,k,v; reused: cross-q, mlp hidden)
  u16*   kvb   = (u16*)(ws + 232*MB);  // 2 x 2^24 bf16 cross k,v (aliased convb)
  u16*   convb = kvb;
  u16*   attno = (u16*)(ws + 296*MB);  // [65536,256] bf16
  const long SEG = 1L<<24;

  k_init<<<1153,256,0,stream>>>(W_so, W_co, W_m2, wSO, stats);

  // ---- transpose + fused GN raw sums (x and c in one launch, 256-t pipelined blocks) ----
  k_transs<<<dim3(32,12,8),256,0,stream>>>(x, c, xT, cT, xstat, cstat);

  // ---- stage 1: self linear attention ----
  k_fold2<<<dim3(1280,8),256,0,stream>>>(W_qkv, nm_g, nm_b, xstat, wQKVb, bQKV, 768, 256, 3, 1.f/65536.f,
                                         W_ckv, nm3_g, nm3_b, cstat, wCKVb, bCKV, 512, 512, 4, 1.f/131072.f);
  k_gemm<true,true,false,false,false,true,false><<<dim3(6,512),256,0,stream>>>(xT, wQKVb, nullptr, qkvb, bQKV, nullptr, nullptr, 256, 768, 196608, 768);
  k_ctx<<<512,256,0,stream>>>(qkvb+SEG, qkvb+2*SEG, part);
  k_ctxred<<<258,256,0,stream>>>(part, ctxb, ksumF);
  k_attnout<<<2048,256,0,stream>>>(qkvb, ctxb, ksumF, attno);
  k_gemm<true,true,false,false,true,false,false><<<dim3(2,512),256,0,stream>>>(attno, wSO, nullptr, convb, b_so, nullptr, so_sum, 256, 256, 0, 0);
  k_gnres<<<1024,256,0,stream>>>(convb, xT, so_sum, x1_sum, sa_g, sa_b);

  // ---- stage 2: cross linear attention ----
  k_fold<<<dim3(256,8),256,0,stream>>>(W_cq, nm1_g, nm1_b, nullptr, x1_sum, wCQb, bCQ, 256, 256, 3, 1.f/65536.f);
  k_gemm<true,true,false,false,false,false,false><<<dim3(2,512),256,0,stream>>>(xT, wCQb, nullptr, qkvb, bCQ, nullptr, nullptr, 256, 256, 65536, 256);
  k_gemm<true,true,false,false,false,true,false><<<dim3(4,512),256,0,stream>>>(cT, wCKVb, nullptr, kvb, bCKV, nullptr, nullptr, 512, 512, 262144, 512);
  k_ctx<<<512,256,0,stream>>>(kvb, kvb+SEG, part);
  k_ctxred<<<258,256,0,stream>>>(part, ctxb, ksumF);
  k_attnout<<<2048,256,0,stream>>>(qkvb, ctxb, ksumF, attno);
  k_gemm<true,true,false,false,true,false,false><<<dim3(2,512),256,0,stream>>>(attno, wCO, nullptr, convb, b_co, nullptr, co_sum, 256, 256, 0, 0);
  k_gnres<<<1024,256,0,stream>>>(convb, xT, co_sum, x2_sum, ca_g, ca_b);

  // ---- stage 3: SiLU MLP ----
  k_fold<<<dim3(640,8),256,0,stream>>>(W_m1, nm2_g, nm2_b, b_m1, x2_sum, wM1b, bM1, 640, 256, 3, 1.f/65536.f);
  k_gemm<true,true,true,false,false,false,false><<<dim3(5,512),256,0,stream>>>(xT, wM1b, nullptr, qkvb, bM1, nullptr, nullptr, 256, 640, 163840, 640);
  // M2: fp32 output written directly transposed to [B,256,T] (k_final fused away)
  k_gemm<false,true,false,true,false,false,true><<<dim3(2,512),256,0,stream>>>(qkvb, wM2, out, nullptr, b_m2, xT, nullptr, 640, 256, 0, 0);
}

// Round 5
// 866.513 us; speedup vs baseline: 1.1248x; 1.0069x over previous
//
#include <hip/hip_runtime.h>
#include <cmath>

typedef unsigned short u16;
typedef __attribute__((ext_vector_type(8))) __bf16 bf16x8;
typedef __attribute__((ext_vector_type(4))) float f32x4;

#define DEV static __device__ __forceinline__

DEV float b2f(u16 u){ union{unsigned i; float f;} v; v.i=((unsigned)u)<<16; return v.f; }
DEV u16 f2b(float f){ union{float f; unsigned i;} v; v.f=f; unsigned r = v.i + 0x7FFFu + ((v.i>>16)&1u); return (u16)(r>>16); }

#define GLL(g,l) __builtin_amdgcn_global_load_lds((const __attribute__((address_space(1))) void*)(g), (__attribute__((address_space(3))) void*)(l), 16, 0, 0)

// ---------------- init: convert W_so|W_co|W_m2 to bf16 + zero stats ----------------
__global__ void k_init(const float* __restrict__ s0,const float* __restrict__ s1,
                       const float* __restrict__ s2, u16* __restrict__ d,
                       float* __restrict__ stats){
  const int bid = blockIdx.x;
  if (bid == 1152){
    #pragma unroll
    for (int j=0;j<12;j++){ const int idx=j*256+threadIdx.x; if (idx<3072) stats[idx]=0.f; }
    return;
  }
  const int i = bid*256 + threadIdx.x;
  const float* s; int off;
  if      (i < 65536){ s=s0; off=0; }
  else if (i < 131072){ s=s1; off=65536; }
  else                { s=s2; off=131072; }
  d[i] = f2b(s[i-off]);
}

// ---------------- GN->conv fold: per-batch weights + bias ----------------
// Wb[b][o][k] = W[o][k]*g[k]*rs[b,gr(k)];  biasb[b][o] = base[o] + sum_k W[o][k]*(beta[k]-mu*rs*g[k])
DEV void fold_body(const float* W, const float* g, const float* beta, const float* base,
                   const float* stats, u16* Wb, float* biasb, int O, int K, int chsh,
                   float inv_n, int o, int b){
  const int tid = threadIdx.x;
  float bp = 0.f;
  for (int k = tid; k < K; k += 256){
    const int gr = k >> chsh;
    const float s = stats[(b*32+gr)*2], s2 = stats[(b*32+gr)*2+1];
    const float mu = s*inv_n;
    const float rs = rsqrtf(s2*inv_n - mu*mu + 1e-5f);
    const float w = W[(long)o*K + k];
    const float gg = g[k]*rs;
    Wb[((long)b*O + o)*K + k] = f2b(w*gg);
    bp += w*(beta[k] - mu*gg);
  }
  __shared__ float red[256];
  red[tid] = bp; __syncthreads();
  for (int off=128; off>0; off>>=1){ if (tid<off) red[tid]+=red[tid+off]; __syncthreads(); }
  if (tid==0) biasb[b*O+o] = red[0] + (base ? base[o] : 0.f);
}

__global__ void k_fold(const float* __restrict__ W, const float* __restrict__ g,
                       const float* __restrict__ beta, const float* __restrict__ base,
                       const float* __restrict__ stats, u16* __restrict__ Wb,
                       float* __restrict__ biasb, int O, int K, int chsh, float inv_n){
  fold_body(W,g,beta,base,stats,Wb,biasb,O,K,chsh,inv_n,blockIdx.x,blockIdx.y);
}

// merged fold for QKV (O1 rows) + CKV (O2 rows)
__global__ void k_fold2(const float* __restrict__ W1, const float* __restrict__ g1,
                        const float* __restrict__ be1, const float* __restrict__ st1,
                        u16* __restrict__ Wb1, float* __restrict__ bb1, int O1, int K1, int chsh1, float inv1,
                        const float* __restrict__ W2, const float* __restrict__ g2,
                        const float* __restrict__ be2, const float* __restrict__ st2,
                        u16* __restrict__ Wb2, float* __restrict__ bb2, int O2, int K2, int chsh2, float inv2){
  const int o = blockIdx.x, b = blockIdx.y;
  if (o < O1) fold_body(W1,g1,be1,nullptr,st1,Wb1,bb1,O1,K1,chsh1,inv1,o,b);
  else        fold_body(W2,g2,be2,nullptr,st2,Wb2,bb2,O2,K2,chsh2,inv2,o-O1,b);
}

// ---------------- transpose [B,C,T] -> [B,T,C] raw bf16 + fused GN raw sums (x and c merged) ----
// Each block: 64 channels x 128 t (2 tiles). ALL global loads issued up front
// (8 float4 per thread in flight) so HBM latency is hidden by MLP, then the two
// LDS transpose/store phases run back-to-back.
__global__ void k_transs(const float* __restrict__ xsrc, const float* __restrict__ csrc,
                         u16* __restrict__ xdst, u16* __restrict__ cdst,
                         float* __restrict__ xstat, float* __restrict__ cstat){
  const int b = blockIdx.z;
  const int gy = blockIdx.y;
  const float* src; u16* dst; float* stat; int C, chsh, c0;
  if (gy < 4){ src=xsrc; dst=xdst; stat=xstat; C=256; chsh=3; c0=gy*64; }
  else       { src=csrc; dst=cdst; stat=cstat; C=512; chsh=4; c0=(gy-4)*64; }
  const int tsup = blockIdx.x*128;
  const int tid = threadIdx.x;
  __shared__ float tile[64][65];
  __shared__ float grp[16];
  if (tid < 16) grp[tid] = 0.f;
  const int ccb = tid>>4, ttl = (tid&15)*4;      // load-side coords
  const int ttr = tid>>4, c4 = (tid&15)*4;       // store-side coords
  const long srow = (long)b*C + c0;
  float s_acc[4]={0.f,0.f,0.f,0.f}, s2_acc[4]={0.f,0.f,0.f,0.f};
  float4 buf0[4], buf1[4];
  #pragma unroll
  for (int p=0;p<4;p++)
    buf0[p] = *(const float4*)&src[(srow + ccb + p*16)*8192 + tsup + ttl];
  #pragma unroll
  for (int p=0;p<4;p++)
    buf1[p] = *(const float4*)&src[(srow + ccb + p*16)*8192 + tsup + 64 + ttl];
  #pragma unroll
  for (int q=0;q<2;q++){
    const int t0 = tsup + q*64;
    #pragma unroll
    for (int p=0;p<4;p++){
      const float4 v = q ? buf1[p] : buf0[p];
      const int cc = ccb + p*16;
      tile[cc][ttl+0]=v.x; tile[cc][ttl+1]=v.y; tile[cc][ttl+2]=v.z; tile[cc][ttl+3]=v.w;
      s_acc[p]  += v.x+v.y+v.z+v.w;
      s2_acc[p] += v.x*v.x+v.y*v.y+v.z*v.z+v.w*v.w;
    }
    __syncthreads();
    #pragma unroll
    for (int p=0;p<4;p++){
      const int tt = ttr + p*16;
      u16 rbi[4];
      #pragma unroll
      for (int j=0;j<4;j++) rbi[j] = f2b(tile[c4+j][tt]);
      ushort4 rv; rv.x=rbi[0]; rv.y=rbi[1]; rv.z=rbi[2]; rv.w=rbi[3];
      *(ushort4*)&dst[((long)b*8192 + t0+tt)*C + c0+c4] = rv;
    }
    __syncthreads();
  }
  // single stats-reduce phase per block (per-channel 16-lane shuffle reduce)
  #pragma unroll
  for (int p=0;p<4;p++){
    float s = s_acc[p], s2 = s2_acc[p];
    #pragma unroll
    for (int m=1; m<16; m<<=1){ s += __shfl_xor(s, m); s2 += __shfl_xor(s2, m); }
    if ((tid&15)==0){
      const int gl = (ccb + p*16) >> chsh;
      atomicAdd(&grp[gl*2],   s);
      atomicAdd(&grp[gl*2+1], s2);
    }
  }
  __syncthreads();
  const int ngr = 64>>chsh;
  if (tid < ngr*2){
    atomicAdd(&stat[((b*32) + (c0>>chsh))*2 + tid], grp[tid]);
  }
}

// ---------------- MFMA GEMM: out[t,o] = sum_k A[t,k]*W[o,k] ----------------
// wsb/bsb: per-batch strides for folded weights/bias (0 for shared)
// TRANS: write fp32 directly in [B,256,T] layout (fuses the final transpose)
template<bool OUTB, bool BIAS, bool SILU, bool RES, bool STATS, bool SPLIT, bool TRANS>
__global__ __launch_bounds__(256,2) void k_gemm(
    const u16* __restrict__ A, const u16* __restrict__ W,
    float* __restrict__ outF, u16* __restrict__ outB,
    const float* __restrict__ bias, const u16* __restrict__ res,
    float* __restrict__ stat, int K, int O, long wsb, int bsb)
{
  __shared__ u16 As[128*64];
  __shared__ u16 Ws[128*64];
  __shared__ float sb[128][2];
  const int tid = threadIdx.x;
  const int wv = tid>>6, lane = tid&63;
  // XCD-chunked bijective swizzle (all grids have nwg % 8 == 0):
  // consecutive fid (round-robin across XCDs) -> contiguous tile chunks per XCD
  const int nwg = (int)(gridDim.x*gridDim.y);
  int fid = (int)(blockIdx.y*gridDim.x + blockIdx.x);
  fid = (fid&7)*(nwg>>3) + (fid>>3);
  const long t0 = (long)(fid / (int)gridDim.x)*128;
  const int o0 = (fid % (int)gridDim.x)*128;
  const int bb = (int)(t0>>13);
  const u16* Wp = W + (long)bb*wsb;
  const int wt = (wv>>1)*64, wo = (wv&1)*64;
  const int lr = lane>>3, lc = (lane&7)*8;
  f32x4 acc[4][4] = {};
  for (int kc = 0; kc < K; kc += 64){
    #pragma unroll
    for (int it = 0; it < 4; ++it){
      const int r = wv*32 + it*8;
      GLL(A + (t0 + r + lr)*(long)K + kc + lc, &As[r*64]);
      GLL(Wp + (long)(o0 + r + lr)*K + kc + lc, &Ws[r*64]);
    }
    __syncthreads();
    #pragma unroll
    for (int ks=0; ks<2; ++ks){
      const int kb = ks*32 + (lane>>4)*8;
      bf16x8 af[4], bfr[4];
      #pragma unroll
      for (int i=0;i<4;i++) af[i]  = *(const bf16x8*)&As[(wt + i*16 + (lane&15))*64 + kb];
      #pragma unroll
      for (int j=0;j<4;j++) bfr[j] = *(const bf16x8*)&Ws[(wo + j*16 + (lane&15))*64 + kb];
      #pragma unroll
      for (int i=0;i<4;i++)
        #pragma unroll
        for (int j=0;j<4;j++)
          acc[i][j] = __builtin_amdgcn_mfma_f32_16x16x32_bf16(af[i], bfr[j], acc[i][j], 0, 0, 0);
    }
    __syncthreads();
  }
  if (STATS){
    if (tid < 128){ sb[tid][0]=0.f; sb[tid][1]=0.f; }
    __syncthreads();
  }
  const int q = lane>>4, cc = lane&15;
  #pragma unroll
  for (int j=0;j<4;j++){
    const int o = o0 + wo + j*16 + cc;
    const float bv = BIAS ? bias[bsb*bb + o] : 0.f;
    float ts=0.f, ts2=0.f;
    #pragma unroll
    for (int i=0;i<4;i++){
      const long tb = t0 + wt + i*16 + q*4;
      if (TRANS){
        float vv[4];
        #pragma unroll
        for (int r=0;r<4;r++){
          float v = acc[i][j][r] + bv;
          if (SILU) v = v * (1.f/(1.f + __expf(-v)));
          if (RES) v += b2f(res[(tb + r)*(long)O + o]);
          vv[r] = v;
        }
        float4 v4; v4.x=vv[0]; v4.y=vv[1]; v4.z=vv[2]; v4.w=vv[3];
        *(float4*)&outF[(((tb>>13)*(long)O + o)<<13) + (tb&8191)] = v4;
      } else {
        #pragma unroll
        for (int r=0;r<4;r++){
          float v = acc[i][j][r] + bv;
          if (SILU) v = v * (1.f/(1.f + __expf(-v)));
          long idx;
          if (SPLIT) idx = ((long)(o>>8)<<24) + (tb + r)*256 + (o&255);
          else       idx = (tb + r)*(long)O + o;
          if (RES) v += b2f(res[idx]);
          if (STATS){ ts += v; ts2 += v*v; }
          if (OUTB) outB[idx] = f2b(v); else outF[idx] = v;
        }
      }
    }
    if (STATS){
      const int ol = wo + j*16 + cc;
      atomicAdd(&sb[ol][0], ts);
      atomicAdd(&sb[ol][1], ts2);
    }
  }
  if (STATS){
    __syncthreads();
    if (tid < 16){
      float u=0.f, u2=0.f;
      #pragma unroll
      for (int j2=0;j2<8;j2++){ u += sb[tid*8+j2][0]; u2 += sb[tid*8+j2][1]; }
      atomicAdd(&stat[(bb*32 + (o0>>3) + tid)*2],   u);
      atomicAdd(&stat[(bb*32 + (o0>>3) + tid)*2+1], u2);
    }
  }
}

// ---------------- ctx partials + per-block ksum partial; dense [65536,256] k/v inputs ----------------
__global__ __launch_bounds__(256,2) void k_ctx(const u16* __restrict__ kp, const u16* __restrict__ vp,
                                               float* __restrict__ part){
  const int tid = threadIdx.x;
  const int b = blockIdx.x >> 6, seg = blockIdx.x & 63;
  const int h = tid>>5, d = tid&31;
  __shared__ u16 kb[16][256];
  __shared__ float vf[16][260];
  float acc[32];
  #pragma unroll
  for (int e=0;e<32;e++) acc[e]=0.f;
  float ks = 0.f;
  const long rb = (long)b*8192 + seg*128;
  const int w = tid>>6, sub = tid&63;
  for (int tc=0; tc<128; tc+=16){
    #pragma unroll
    for (int p=0;p<4;p++){
      const int row = p*4 + w;
      const long rowbase = (rb + tc + row)*256;
      if (sub < 32){
        uint4 val = *(const uint4*)(kp + rowbase + sub*8);
        *(uint4*)&kb[row][sub*8] = val;
      } else {
        const int s2 = sub-32;
        uint4 val = *(const uint4*)(vp + rowbase + s2*8);
        const u16* vs = (const u16*)&val;
        float4 f0 = {b2f(vs[0]),b2f(vs[1]),b2f(vs[2]),b2f(vs[3])};
        float4 f1 = {b2f(vs[4]),b2f(vs[5]),b2f(vs[6]),b2f(vs[7])};
        *(float4*)&vf[row][s2*8] = f0;
        *(float4*)&vf[row][s2*8+4] = f1;
      }
    }
    __syncthreads();
    #pragma unroll
    for (int r=0;r<16;r++){
      const float kpv = __expf(b2f(kb[r][h*32+d]));
      ks += kpv;
      #pragma unroll
      for (int e4=0;e4<8;e4++){
        const float4 v4 = *(const float4*)&vf[r][h*32+e4*4];
        acc[e4*4+0] += kpv*v4.x; acc[e4*4+1] += kpv*v4.y;
        acc[e4*4+2] += kpv*v4.z; acc[e4*4+3] += kpv*v4.w;
      }
    }
    __syncthreads();
  }
  float* pb = part + (long)blockIdx.x*8448;
  #pragma unroll
  for (int e=0;e<32;e++) pb[e*256 + tid] = acc[e];
  pb[8192 + tid] = ks;
}

// ---------------- reduce ctx partials + ksum partials ----------------
__global__ void k_ctxred(const float* __restrict__ part, float* __restrict__ ctx,
                         float* __restrict__ ksumF){
  if (blockIdx.x >= 256){
    const int j = (blockIdx.x-256)*256 + threadIdx.x;
    #pragma unroll
    for (int q=0;q<4;q++){
      const int idx = j*4+q;
      const int b = idx>>8, cch = idx&255;
      float s=0.f;
      for (int g=0; g<64; g++) s += part[((long)(b*64+g))*8448 + 8192 + cch];
      ksumF[idx] = s;
    }
    return;
  }
  const int i = blockIdx.x*256 + threadIdx.x;
  const int b = i>>13, r = i&8191;
  float s=0.f;
  for (int g=0; g<64; g++) s += part[((long)(b*64+g))*8448 + r];
  ctx[i] = s;
}

// ---------------- attn out: q-softmax contraction against ctx/ksum; q dense [65536,256] ----
__global__ void k_attnout(const u16* __restrict__ q, const float* __restrict__ ctx,
                          const float* __restrict__ ksumF, u16* __restrict__ out){
  const int b = blockIdx.x >> 8, t0 = (blockIdx.x & 255)*32;
  __shared__ float cs[8512];   // [h][d][e] strides 1064/33/1
  for (int i=threadIdx.x; i<8192; i+=256){
    const int e=i>>8, cch=i&255;
    cs[(cch>>5)*1064 + (cch&31)*33 + e] = ctx[(b<<13) + i] / ksumF[b*256 + cch];
  }
  __syncthreads();
  const int t = t0 + (threadIdx.x>>3), h = threadIdx.x&7;
  const u16* qp = q + ((long)b*8192 + t)*256 + h*32;
  uint4 qv[4];
  #pragma unroll
  for (int j=0;j<4;j++) qv[j] = ((const uint4*)qp)[j];
  const u16* qs = (const u16*)qv;
  float qe[32]; float ssum = 0.f;
  #pragma unroll
  for (int dd=0; dd<32; dd++){ qe[dd] = __expf(b2f(qs[dd])); ssum += qe[dd]; }
  const float inv = 0.17677669529663687f / ssum;
  float o[32];
  #pragma unroll
  for (int e=0;e<32;e++) o[e]=0.f;
  const float* ch = &cs[h*1064];
  #pragma unroll
  for (int dd=0; dd<32; dd++){
    const float w = qe[dd]*inv;
    #pragma unroll
    for (int e=0;e<32;e++) o[e] += w * ch[dd*33+e];
  }
  u16 ob[32];
  #pragma unroll
  for (int e=0;e<32;e++) ob[e] = f2b(o[e]);
  uint4* op = (uint4*)(out + ((long)b*8192 + t)*256 + h*32);
  const uint4* obv = (const uint4*)ob;
  #pragma unroll
  for (int j=0;j<4;j++) op[j] = obv[j];
}

// ---------------- x_new = GN(conv)*g+b + x (bf16 residual, in-place) + stats of x_new ----------------
__global__ void k_gnres(const u16* __restrict__ conv, u16* __restrict__ xr,
                        const float* __restrict__ sums_in, float* __restrict__ sums_out,
                        const float* __restrict__ g, const float* __restrict__ bt){
  const int blk = blockIdx.x;
  const int b = blk>>7;
  const long base = (long)blk*4096;
  const int tid = threadIdx.x;
  const int c0 = (tid<<2)&255;
  const int gr = c0>>3;
  const float s = sums_in[(b*32+gr)*2], s2 = sums_in[(b*32+gr)*2+1];
  const float mu = s*(1.f/65536.f);
  const float rs = rsqrtf(s2*(1.f/65536.f) - mu*mu + 1e-5f);
  float gg[4], bb[4];
  #pragma unroll
  for (int j=0;j<4;j++){ gg[j] = g[c0+j]*rs; bb[j] = bt[c0+j] - mu*gg[j]; }
  float ts=0.f, ts2=0.f;
  for (int it=0; it<16; ++it){
    const long i4 = base + it*256 + tid;
    ushort4 cv = ((const ushort4*)conv)[i4];
    ushort4 rv = ((const ushort4*)xr)[i4];
    float ov[4];
    const float ci[4] = {b2f(cv.x),b2f(cv.y),b2f(cv.z),b2f(cv.w)};
    const float ri[4] = {b2f(rv.x),b2f(rv.y),b2f(rv.z),b2f(rv.w)};
    #pragma unroll
    for (int j=0;j<4;j++){
      ov[j] = ci[j]*gg[j] + bb[j] + ri[j];
      ts += ov[j]; ts2 += ov[j]*ov[j];
    }
    ushort4 o4; o4.x=f2b(ov[0]); o4.y=f2b(ov[1]); o4.z=f2b(ov[2]); o4.w=f2b(ov[3]);
    ((ushort4*)xr)[i4] = o4;
  }
  __shared__ float grp[32][2];
  if (tid<32){ grp[tid][0]=0.f; grp[tid][1]=0.f; }
  __syncthreads();
  atomicAdd(&grp[gr][0], ts);
  atomicAdd(&grp[gr][1], ts2);
  __syncthreads();
  if (tid<32){
    atomicAdd(&sums_out[(b*32+tid)*2],   grp[tid][0]);
    atomicAdd(&sums_out[(b*32+tid)*2+1], grp[tid][1]);
  }
}

extern "C" void kernel_launch(void* const* d_in, const int* in_sizes, int n_in,
                              void* d_out, int out_size, void* d_ws, size_t ws_size,
                              hipStream_t stream){
  (void)in_sizes; (void)n_in; (void)out_size; (void)ws_size;
  const float* x   = (const float*)d_in[0];
  const float* c   = (const float*)d_in[1];
  const float* W_qkv=(const float*)d_in[2];
  const float* W_so =(const float*)d_in[3];
  const float* b_so =(const float*)d_in[4];
  const float* sa_g =(const float*)d_in[5];
  const float* sa_b =(const float*)d_in[6];
  const float* W_cq =(const float*)d_in[7];
  const float* W_ckv=(const float*)d_in[8];
  const float* W_co =(const float*)d_in[9];
  const float* b_co =(const float*)d_in[10];
  const float* ca_g =(const float*)d_in[11];
  const float* ca_b =(const float*)d_in[12];
  const float* W_m1 =(const float*)d_in[13];
  const float* b_m1 =(const float*)d_in[14];
  const float* W_m2 =(const float*)d_in[15];
  const float* b_m2 =(const float*)d_in[16];
  const float* nm_g =(const float*)d_in[17];
  const float* nm_b =(const float*)d_in[18];
  const float* nm1_g=(const float*)d_in[19];
  const float* nm1_b=(const float*)d_in[20];
  const float* nm2_g=(const float*)d_in[21];
  const float* nm2_b=(const float*)d_in[22];
  const float* nm3_g=(const float*)d_in[23];
  const float* nm3_b=(const float*)d_in[24];
  float* out = (float*)d_out;

  char* ws = (char*)d_ws;
  const size_t MB = 1024ull*1024ull;
  // non-folded weights (bf16)
  u16* wSO = (u16*)ws;                 // 65536
  u16* wCO = wSO + 65536;              // 65536
  u16* wM2 = wCO + 65536;              // 163840
  // stats
  float* stats = (float*)(ws + 1*MB);
  float* xstat = stats;                // 512
  float* cstat = stats + 512;          // 512
  float* so_sum= stats + 1024;
  float* x1_sum= stats + 1536;
  float* co_sum= stats + 2048;
  float* x2_sum= stats + 2560;
  float* ksumF = stats + 3072;         // 2048
  float* ctxb  = stats + 8192;         // 65536
  // folded biases (fp32)
  float* bQKV = (float*)(ws + 2*MB);   // 8*768
  float* bCKV = bQKV + 6144;           // 8*512
  float* bCQ  = bCKV + 4096;           // 8*256
  float* bM1  = bCQ + 2048;            // 8*640
  // folded per-batch weights (bf16)
  u16* wQKVb = (u16*)(ws + 3*MB);      // 8*768*256 = 3 MB
  u16* wCKVb = (u16*)(ws + 6*MB);      // 8*512*512 = 4 MB
  u16* wCQb  = (u16*)(ws + 10*MB);     // 8*256*256 = 1 MB
  u16* wM1b  = (u16*)(ws + 11*MB);     // 8*640*256 = 2.5 MB
  // streams
  u16*   xT    = (u16*)(ws + 16*MB);   // [65536,256] bf16 raw residual (in-place)
  u16*   cT    = (u16*)(ws + 48*MB);   // [65536,512] bf16 raw transposed c
  float* part  = (float*)(ws + 112*MB);// [512][8448] fp32 partials
  u16*   qkvb  = (u16*)(ws + 136*MB);  // 3 x 2^24 bf16 (q,k,v; reused: cross-q, mlp hidden)
  u16*   kvb   = (u16*)(ws + 232*MB);  // 2 x 2^24 bf16 cross k,v (aliased convb)
  u16*   convb = kvb;
  u16*   attno = (u16*)(ws + 296*MB);  // [65536,256] bf16
  const long SEG = 1L<<24;

  k_init<<<1153,256,0,stream>>>(W_so, W_co, W_m2, wSO, stats);

  // ---- transpose + fused GN raw sums (x and c in one launch, full upfront prefetch) ----
  k_transs<<<dim3(64,12,8),256,0,stream>>>(x, c, xT, cT, xstat, cstat);

  // ---- stage 1: self linear attention ----
  k_fold2<<<dim3(1280,8),256,0,stream>>>(W_qkv, nm_g, nm_b, xstat, wQKVb, bQKV, 768, 256, 3, 1.f/65536.f,
                                         W_ckv, nm3_g, nm3_b, cstat, wCKVb, bCKV, 512, 512, 4, 1.f/131072.f);
  k_gemm<true,true,false,false,false,true,false><<<dim3(6,512),256,0,stream>>>(xT, wQKVb, nullptr, qkvb, bQKV, nullptr, nullptr, 256, 768, 196608, 768);
  k_ctx<<<512,256,0,stream>>>(qkvb+SEG, qkvb+2*SEG, part);
  k_ctxred<<<258,256,0,stream>>>(part, ctxb, ksumF);
  k_attnout<<<2048,256,0,stream>>>(qkvb, ctxb, ksumF, attno);
  k_gemm<true,true,false,false,true,false,false><<<dim3(2,512),256,0,stream>>>(attno, wSO, nullptr, convb, b_so, nullptr, so_sum, 256, 256, 0, 0);
  k_gnres<<<1024,256,0,stream>>>(convb, xT, so_sum, x1_sum, sa_g, sa_b);

  // ---- stage 2: cross linear attention ----
  k_fold<<<dim3(256,8),256,0,stream>>>(W_cq, nm1_g, nm1_b, nullptr, x1_sum, wCQb, bCQ, 256, 256, 3, 1.f/65536.f);
  k_gemm<true,true,false,false,false,false,false><<<dim3(2,512),256,0,stream>>>(xT, wCQb, nullptr, qkvb, bCQ, nullptr, nullptr, 256, 256, 65536, 256);
  k_gemm<true,true,false,false,false,true,false><<<dim3(4,512),256,0,stream>>>(cT, wCKVb, nullptr, kvb, bCKV, nullptr, nullptr, 512, 512, 262144, 512);
  k_ctx<<<512,256,0,stream>>>(kvb, kvb+SEG, part);
  k_ctxred<<<258,256,0,stream>>>(part, ctxb, ksumF);
  k_attnout<<<2048,256,0,stream>>>(qkvb, ctxb, ksumF, attno);
  k_gemm<true,true,false,false,true,false,false><<<dim3(2,512),256,0,stream>>>(attno, wCO, nullptr, convb, b_co, nullptr, co_sum, 256, 256, 0, 0);
  k_gnres<<<1024,256,0,stream>>>(convb, xT, co_sum, x2_sum, ca_g, ca_b);

  // ---- stage 3: SiLU MLP ----
  k_fold<<<dim3(640,8),256,0,stream>>>(W_m1, nm2_g, nm2_b, b_m1, x2_sum, wM1b, bM1, 640, 256, 3, 1.f/65536.f);
  k_gemm<true,true,true,false,false,false,false><<<dim3(5,512),256,0,stream>>>(xT, wM1b, nullptr, qkvb, bM1, nullptr, nullptr, 256, 640, 163840, 640);
  // M2: fp32 output written directly transposed to [B,256,T] (k_final fused away)
  k_gemm<false,true,false,true,false,false,true><<<dim3(2,512),256,0,stream>>>(qkvb, wM2, out, nullptr, b_m2, xT, nullptr, 640, 256, 0, 0);
}